// Round 11
// baseline (5180.515 us; speedup 1.0000x reference)
//
#include <hip/hip_runtime.h>
#include <math.h>

#define NB 16
#define WD 128

typedef __bf16 bf16_t;
typedef __bf16 bf16x8 __attribute__((ext_vector_type(8)));
typedef __bf16 bf16x4 __attribute__((ext_vector_type(4)));
typedef float f32x4 __attribute__((ext_vector_type(4)));

// ---------------- zero helper ----------------
__global__ void zero_k(float* __restrict__ p, int n) {
  int i = blockIdx.x * 256 + threadIdx.x;
  if (i < n) p[i] = 0.f;
}

// ---------------- split input into data / clipped mask ----------------
__global__ void split_k(const float* __restrict__ x, float* __restrict__ data,
                        float* __restrict__ mask) {
  const int HW = 256 * 128;
  int i = blockIdx.x * 256 + threadIdx.x;
  if (i >= NB * HW) return;
  int n = i / HW, rem = i % HW;
  data[i] = x[(size_t)(n * 2) * HW + rem];
  float mv = x[(size_t)(n * 2 + 1) * HW + rem];
  mask[i] = fminf(fmaxf(mv, 0.f), 1.f);
}

// ---------------- mask 3x3 sum (pad=1) -> scale + mask_next ----------------
__global__ void maskscale_k(const float* __restrict__ m, float* __restrict__ scale,
                            float* __restrict__ mnext, int H, float Ci) {
  int i = blockIdx.x * 256 + threadIdx.x;
  int tot = NB * H * WD;
  if (i >= tot) return;
  int x = i % WD;
  int t = i / WD;
  int y = t % H;
  int n = t / H;
  const float* mn_ = m + (size_t)n * H * WD;
  float s = 0.f;
#pragma unroll
  for (int dy = -1; dy <= 1; dy++) {
    int yy = y + dy;
#pragma unroll
    for (int dx = -1; dx <= 1; dx++) {
      int xx = x + dx;
      float v = 1.0f;
      if (yy >= 0 && yy < H && xx >= 0 && xx < WD) v = mn_[yy * WD + xx];
      s += v;
    }
  }
  float valid = Ci * s;
  float sc = (9.0f * Ci) / fmaxf(valid, 1.0f);
  scale[i] = sc;
  mnext[i] = (valid <= 0.0f) ? 0.f : 1.f;
}

// ---------------- mask (2,1) maxpool ----------------
__global__ void maskpool_k(const float* __restrict__ mn, float* __restrict__ mp, int H) {
  int Hp = H / 2;
  int i = blockIdx.x * 256 + threadIdx.x;
  int tot = NB * Hp * WD;
  if (i >= tot) return;
  int x = i % WD;
  int t = i / WD;
  int yo = t % Hp;
  int n = t / Hp;
  mp[i] = fmaxf(mn[((size_t)n * H + 2 * yo) * WD + x],
                mn[((size_t)n * H + 2 * yo + 1) * WD + x]);
}

// ---------------- stage-1 direct conv (Ci=1), NHWC bf16 out ----------------
__global__ void pconv1_k(const float* __restrict__ data, const float* __restrict__ mask,
                         const float* __restrict__ w, const float* __restrict__ b,
                         const float* __restrict__ scale, const float* __restrict__ mnext,
                         bf16_t* __restrict__ y) {
  __shared__ float ws[720];
  __shared__ float bs[80];
  for (int i = threadIdx.x; i < 720; i += 256) ws[i] = w[i];
  if (threadIdx.x < 80) bs[threadIdx.x] = b[threadIdx.x];
  __syncthreads();
  const int H = 256;
  int p = blockIdx.x * 256 + threadIdx.x;
  int x = p % WD;
  int t = p / WD;
  int yy = t % H;
  int n = t / H;
  const float* dn = data + (size_t)n * H * WD;
  const float* mn = mask + (size_t)n * H * WD;
  float v[9];
#pragma unroll
  for (int dy = 0; dy < 3; dy++) {
    int yv = yy - 1 + dy;
#pragma unroll
    for (int dx = 0; dx < 3; dx++) {
      int xv = x - 1 + dx;
      float u = 0.f;
      if (yv >= 0 && yv < H && xv >= 0 && xv < WD)
        u = dn[yv * WD + xv] * mn[yv * WD + xv];
      v[dy * 3 + dx] = u;
    }
  }
  float sc = scale[p], mx = mnext[p];
  bf16_t* yp = y + (size_t)p * 80;
#pragma unroll
  for (int c8 = 0; c8 < 10; ++c8) {
    bf16x8 o;
#pragma unroll
    for (int j = 0; j < 8; ++j) {
      int co = c8 * 8 + j;
      float s = 0.f;
#pragma unroll
      for (int tt = 0; tt < 9; ++tt) s += ws[co * 9 + tt] * v[tt];
      o[j] = (bf16_t)((s * sc + bs[co]) * mx);
    }
    *(bf16x8*)(yp + c8 * 8) = o;
  }
}

// ---------------- BN stats over NHWC bf16 (stage 1) ----------------
__global__ void bnstats_k(const bf16_t* __restrict__ y, float* __restrict__ sums,
                          int C, int P) {
  int c = threadIdx.x;  // blockDim 128
  if (c >= C) return;
  float s = 0.f, q = 0.f;
  for (int p = blockIdx.x; p < P; p += gridDim.x) {
    float v = (float)y[(size_t)p * C + c];
    s += v;
    q += v * v;
  }
  atomicAdd(&sums[c], s);
  atomicAdd(&sums[C + c], q);
}

// ---------------- weight transform: w[co][ci][3][3] fp32 -> wt2 bf16 ----------------
// wt2 index: (((tap*NCB + cb)*4 + g)*Co_pad + co)*8 + j   (ci = cb*32 + g*8 + j)
__global__ void wtrans_k(const float* __restrict__ w, bf16_t* __restrict__ wt2,
                         int Ci, int Co, int NCB, int Co_pad) {
  int idx = blockIdx.x * 256 + threadIdx.x;
  int total = 9 * NCB * Co_pad * 32;
  if (idx >= total) return;
  int j = idx & 7;
  int rest = idx >> 3;
  int co = rest % Co_pad;
  int rest2 = rest / Co_pad;
  int g = rest2 & 3;
  int rest3 = rest2 >> 2;
  int cb = rest3 % NCB;
  int tap = rest3 / NCB;
  int ci = cb * 32 + g * 8 + j;
  float v = 0.f;
  if (co < Co && ci < Ci) v = w[((size_t)co * Ci + ci) * 9 + tap];
  wt2[idx] = (bf16_t)v;
}

// ---------------- MFMA implicit-GEMM 3x3 conv (stages 2-4) ----------------
// Round-11: 4 output rows per block -> 128 co x 512 px. Wave = 64 co x 2 rows,
// acc[4][2][8] (256 VGPRs). Per (cb,dy) event: A 24KB (3 dx taps); B staged
// once per cb (6 input rows, 54KB). 192 MFMA/wave/event (2x r10), half the
// blocks -> half the drains per CU. Dynamic LDS 78KB, 2 blocks/CU (156KB).
__global__ __launch_bounds__(256, 2) void convmfma_k(
    const bf16_t* __restrict__ xmT, const bf16_t* __restrict__ wt2,
    const float* __restrict__ bias, const float* __restrict__ scale,
    const float* __restrict__ mnext, bf16_t* __restrict__ y,
    float* __restrict__ sums, int H, int NCB, int Co, int Co_pad) {
  extern __shared__ __align__(16) bf16_t smem[];
  bf16_t* Ab = smem;           // 12288 elems: 3 dx taps x [g][co128][8]
  bf16_t* Bb = smem + 12288;   // 27648 elems: 6 input rows x 9 chunks
  const int tid = threadIdx.x;
  const int lane = tid & 63;
  const int wave = tid >> 6;
  const int wm = wave >> 1;  // co half
  const int wn = wave & 1;   // row-pair index
  const int g = lane >> 4;   // k-group of 8
  const int ln = lane & 15;  // frag row/col
  const int coTile = blockIdx.x * 128;
  const int Hq = H >> 2;
  const int bx = blockIdx.y;  // n*Hq + yquad
  const int n = bx / Hq, y0 = (bx % Hq) * 4;

  f32x4 acc[4][2][8];
#pragma unroll
  for (int mf = 0; mf < 4; mf++)
#pragma unroll
    for (int j = 0; j < 2; j++)
#pragma unroll
      for (int nf = 0; nf < 8; nf++) acc[mf][j][nf] = (f32x4)(0.f);

  const size_t cbStride = 4608;  // elems per (row, cb) slice
  const size_t rowStrideG = (size_t)NCB * cbStride;
  // padded row p holds input row p-1; outputs y0..y0+3 need padded y0..y0+5
  const size_t gRow0 = ((size_t)n * (H + 2) + y0) * rowStrideG;
  const size_t laneOff = (size_t)lane * 8;  // identity: lane L -> L*16B

  for (int cb = 0; cb < NCB; ++cb) {
#pragma unroll
    for (int dy = 0; dy < 3; ++dy) {
      __syncthreads();  // previous event's LDS reads done
      if (dy == 0) {
        // stage B: 6 padded rows (y0..y0+5) of this cb, 54 chunks
        const bf16_t* bsrc = xmT + gRow0 + (size_t)cb * cbStride;
        for (int c = wave; c < 54; c += 4) {
          int row = c / 9, chk = c - row * 9;
          __builtin_amdgcn_global_load_lds(
              (const __attribute__((address_space(1))) void*)(
                  bsrc + (size_t)row * rowStrideG + chk * 512 + laneOff),
              (__attribute__((address_space(3))) void*)(&Bb[c * 512]), 16, 0, 0);
        }
      }
      // stage A: taps dy*3+{0,1,2}, 24 chunks
      for (int c = wave; c < 24; c += 4) {
        int tl = c >> 3, cc = c & 7;
        int tap = dy * 3 + tl;
        const bf16_t* asrc =
            wt2 + ((((size_t)tap * NCB + cb) * 4 + (cc >> 1)) * Co_pad + coTile +
                   (cc & 1) * 64) * 8;
        __builtin_amdgcn_global_load_lds(
            (const __attribute__((address_space(1))) void*)(asrc + laneOff),
            (__attribute__((address_space(3))) void*)(&Ab[tl * 4096 + cc * 512]), 16,
            0, 0);
      }
      __syncthreads();  // staging visible

#pragma unroll
      for (int dx = 0; dx < 3; ++dx) {
        bf16x8 a[4];
#pragma unroll
        for (int mf = 0; mf < 4; ++mf)
          a[mf] =
              *(const bf16x8*)(Ab + dx * 4096 + (g * 128 + wm * 64 + mf * 16 + ln) * 8);
#pragma unroll
        for (int j = 0; j < 2; ++j) {
          const bf16_t* brow = Bb + (size_t)(wn * 2 + j + dy) * 4608;
#pragma unroll
          for (int nf = 0; nf < 8; ++nf) {
            int colx = nf * 16 + ln + dx;
            bf16x8 b =
                *(const bf16x8*)(brow + ((colx >> 4) * 4 + g) * 128 + (colx & 15) * 8);
#pragma unroll
            for (int mf = 0; mf < 4; ++mf)
              acc[mf][j][nf] = __builtin_amdgcn_mfma_f32_16x16x32_bf16(a[mf], b,
                                                                       acc[mf][j][nf],
                                                                       0, 0, 0);
          }
        }
      }
    }
  }

  // epilogue: partial-conv scale + bias + mask, write NHWC bf16, BN stats
#pragma unroll
  for (int mf = 0; mf < 4; ++mf) {
    if (coTile + wm * 64 + mf * 16 >= Co) continue;  // padded frag
    int coB = coTile + wm * 64 + mf * 16 + g * 4;
    f32x4 bias4 = *(const f32x4*)&bias[coB];
    f32x4 s4 = (f32x4)(0.f), q4 = (f32x4)(0.f);
#pragma unroll
    for (int j = 0; j < 2; ++j) {
      const int yrow = y0 + wn * 2 + j;
      const int pixBase = (n * H + yrow) * WD;
#pragma unroll
      for (int nf = 0; nf < 8; ++nf) {
        int x = nf * 16 + ln;
        float sc = scale[pixBase + x], mk = mnext[pixBase + x];
        f32x4 v;
        bf16x4 o;
#pragma unroll
        for (int r = 0; r < 4; ++r) {
          v[r] = (acc[mf][j][nf][r] * sc + bias4[r]) * mk;
          o[r] = (bf16_t)v[r];
        }
        *(bf16x4*)&y[(size_t)(pixBase + x) * Co + coB] = o;
        s4 += v;
        q4 += v * v;
      }
    }
#pragma unroll
    for (int off = 1; off < 16; off <<= 1) {
#pragma unroll
      for (int r = 0; r < 4; ++r) {
        float ts = s4[r], tq = q4[r];
        s4[r] = ts + __shfl_xor(ts, off);
        q4[r] = tq + __shfl_xor(tq, off);
      }
    }
    if (ln == 0) {
#pragma unroll
      for (int r = 0; r < 4; ++r) {
        atomicAdd(&sums[coB + r], s4[r]);
        atomicAdd(&sums[Co + coB + r], q4[r]);
      }
    }
  }
}

// ---------------- BN finalize ----------------
__global__ void bnfin_k(const float* __restrict__ sums, const float* __restrict__ g,
                        const float* __restrict__ be, float* __restrict__ ab, int Co,
                        float invCount) {
  int c = blockIdx.x * 64 + threadIdx.x;
  if (c >= Co) return;
  float mean = sums[c] * invCount;
  float var = sums[Co + c] * invCount - mean * mean;
  float rs = rsqrtf(var + 1e-5f);
  float a = g[c] * rs;
  ab[c] = a;
  ab[Co + c] = be[c] - mean * a;
}

// ---------------- BN + ReLU + (2,1) pool + mask -> chunked padded xmT ----------------
// out layout: [n][Hp+2][NCBn][9 chunks][g][col16][8]
__global__ void bnpool_k(const bf16_t* __restrict__ y, const float* __restrict__ ab,
                         const float* __restrict__ mp, bf16_t* __restrict__ out, int C,
                         int NCBn, int H) {
  int Hp = H / 2;
  int Cq = C / 8;
  int tid = blockIdx.x * 256 + threadIdx.x;
  int total = NB * Hp * WD * Cq;
  if (tid >= total) return;
  int c8 = tid % Cq;
  int t = tid / Cq;
  int x = t % WD;
  t /= WD;
  int yo = t % Hp;
  int n = t / Hp;
  int c = c8 * 8;
  const bf16_t* p0 = y + ((size_t)((n * H + 2 * yo) * WD + x)) * C + c;
  const bf16_t* p1 = p0 + (size_t)WD * C;
  float mpv = mp[(n * Hp + yo) * WD + x];
  bf16x8 v0 = *(const bf16x8*)p0;
  bf16x8 v1 = *(const bf16x8*)p1;
  bf16x8 o;
#pragma unroll
  for (int j = 0; j < 8; ++j) {
    float a = ab[c + j], sh = ab[C + c + j];
    float f0 = (float)v0[j] * a + sh;
    float f1 = (float)v1[j] * a + sh;
    o[j] = (bf16_t)(fmaxf(fmaxf(f0, f1), 0.f) * mpv);
  }
  int cb = c >> 5;           // 32-ci block
  int gg = (c & 31) >> 3;    // k-group within block
  int col = x + 1;           // stored col (1..128)
  int chk = col >> 4, lcol = col & 15;
  *(bf16x8*)&out[((((size_t)n * (Hp + 2) + yo + 1) * NCBn + cb) * 9 + chk) * 512 +
                 gg * 128 + lcol * 8] = o;
}

// ---------------- stage-4: BN + ReLU + pool + global mean -> feat ----------------
__global__ void bnfeat_k(const bf16_t* __restrict__ y, const float* __restrict__ ab,
                         float* __restrict__ feat) {
  int n = blockIdx.x, cc = blockIdx.y, yo = blockIdx.z;
  int c = cc * 128 + threadIdx.x;  // C = 640
  float a = ab[c], sh = ab[640 + c];
  float s = 0.f;
  for (int x = 0; x < WD; ++x) {
    size_t p0 = ((size_t)(n * 32 + 2 * yo) * WD + x) * 640 + c;
    float v0 = (float)y[p0] * a + sh;
    float v1 = (float)y[p0 + (size_t)WD * 640] * a + sh;
    s += fmaxf(fmaxf(v0, v1), 0.f);
  }
  atomicAdd(&feat[n * 640 + c], s * (1.f / 2048.f));
}

// ---------------- fc1 (640->256) + relu ----------------
__global__ void fc1_k(const float* __restrict__ feat, const float* __restrict__ fw,
                      const float* __restrict__ fb, float* __restrict__ z1) {
  int n = blockIdx.x;
  int o = threadIdx.x;
  const float* f = feat + n * 640;
  const float* wr = fw + o * 640;
  float s = fb[o];
  for (int k = 0; k < 640; k++) s += f[k] * wr[k];
  z1[n * 256 + o] = fmaxf(s, 0.f);
}

// ---------------- fc2 (256->128) + relu + head + sigmoid ----------------
__global__ void fc2h_k(const float* __restrict__ z1, const float* __restrict__ fw2,
                       const float* __restrict__ fb2, const float* __restrict__ hw,
                       const float* __restrict__ hb, float* __restrict__ out) {
  int n = blockIdx.x;
  int o = threadIdx.x;
  const float* zr = z1 + n * 256;
  const float* wr = fw2 + o * 256;
  float s = fb2[o];
  for (int k = 0; k < 256; k++) s += zr[k] * wr[k];
  s = fmaxf(s, 0.f) * hw[o];
#pragma unroll
  for (int off = 32; off >= 1; off >>= 1) s += __shfl_down(s, off, 64);
  __shared__ float red[2];
  if ((threadIdx.x & 63) == 0) red[threadIdx.x >> 6] = s;
  __syncthreads();
  if (threadIdx.x == 0) {
    float t = red[0] + red[1] + hb[0];
    out[n] = 1.f / (1.f + expf(-t));
  }
}

extern "C" void kernel_launch(void* const* d_in, const int* in_sizes, int n_in,
                              void* d_out, int out_size, void* d_ws, size_t ws_size,
                              hipStream_t stream) {
  const float* x = (const float*)d_in[0];
  const float* wgt[4] = {(const float*)d_in[1], (const float*)d_in[5],
                         (const float*)d_in[9], (const float*)d_in[13]};
  const float* bias[4] = {(const float*)d_in[2], (const float*)d_in[6],
                          (const float*)d_in[10], (const float*)d_in[14]};
  const float* gam[4] = {(const float*)d_in[3], (const float*)d_in[7],
                         (const float*)d_in[11], (const float*)d_in[15]};
  const float* bet[4] = {(const float*)d_in[4], (const float*)d_in[8],
                         (const float*)d_in[12], (const float*)d_in[16]};
  const float* fw1 = (const float*)d_in[17];
  const float* fb1 = (const float*)d_in[18];
  const float* fw2 = (const float*)d_in[19];
  const float* fb2 = (const float*)d_in[20];
  const float* hw = (const float*)d_in[21];
  const float* hb = (const float*)d_in[22];

  // allow 78KB dynamic LDS for the conv kernel (host-side, capture-safe)
  static bool attrSet = false;
  if (!attrSet) {
    hipFuncSetAttribute((const void*)convmfma_k,
                        hipFuncAttributeMaxDynamicSharedMemorySize, 79872);
    attrSet = true;
  }

  char* base = (char*)d_ws;
  size_t off = 0;
  auto alloc = [&](size_t bytes) {
    char* p = base + off;
    off += (bytes + 255) & ~(size_t)255;
    return p;
  };
  bf16_t* bufY = (bf16_t*)alloc(83886080);  // 41,943,040 bf16
  const size_t xmtElems = 28786688;         // 16*130*3*4608 + 32768 slack
  bf16_t* xmT0 = (bf16_t*)alloc(xmtElems * 2);
  bf16_t* xmT1 = (bf16_t*)alloc(xmtElems * 2);
  bf16_t* wt2 = (bf16_t*)alloc(3686400);
  float* data = (float*)alloc(2097152);
  float* mask0 = (float*)alloc(2097152);
  float* mask1 = (float*)alloc(2097152);
  float* scaleB = (float*)alloc(2097152);
  float* mnextB = (float*)alloc(2097152);
  float* sums = (float*)alloc(5120);
  float* bnab = (float*)alloc(5120);
  float* feat = (float*)alloc(40960);
  float* z1 = (float*)alloc(16384);

  // zero xmT0+xmT1 (contiguous) and feat
  {
    int nf = (int)(xmtElems * 2 * 2 / 4);  // both buffers as floats
    zero_k<<<(nf + 255) / 256, 256, 0, stream>>>((float*)xmT0, nf);
    zero_k<<<40, 256, 0, stream>>>(feat, 10240);
  }

  // split input
  split_k<<<(NB * 256 * 128 + 255) / 256, 256, 0, stream>>>(x, data, mask0);

  // ---------- stage 1 (direct, Ci=1, Co=80, H=256) ----------
  {
    int H = 256;
    int tot = NB * H * WD;
    maskscale_k<<<(tot + 255) / 256, 256, 0, stream>>>(mask0, scaleB, mnextB, H, 1.0f);
    zero_k<<<1, 256, 0, stream>>>(sums, 160);
    pconv1_k<<<tot / 256, 256, 0, stream>>>(data, mask0, wgt[0], bias[0], scaleB,
                                            mnextB, bufY);
    bnstats_k<<<512, 128, 0, stream>>>(bufY, sums, 80, NB * H * WD);
    bnfin_k<<<2, 64, 0, stream>>>(sums, gam[0], bet[0], bnab, 80,
                                  1.0f / (NB * (float)H * WD));
    maskpool_k<<<(NB * (H / 2) * WD + 255) / 256, 256, 0, stream>>>(mnextB, mask1, H);
    int totp = NB * (H / 2) * WD * (80 / 8);
    bnpool_k<<<(totp + 255) / 256, 256, 0, stream>>>(bufY, bnab, mask1, xmT0, 80, 3, H);
  }

  // ---------- stages 2-4 (MFMA implicit GEMM) ----------
  const int CiS[3] = {80, 160, 320};
  const int NCBS[3] = {3, 5, 10};
  const int CoS[3] = {160, 320, 640};
  const int CopS[3] = {256, 384, 640};
  const int HS[3] = {128, 64, 32};
  bf16_t* xin[3] = {xmT0, xmT1, xmT0};
  bf16_t* xout[3] = {xmT1, xmT0, nullptr};
  float* mIn[3] = {mask1, mask0, mask1};
  float* mOut[3] = {mask0, mask1, nullptr};

  for (int s = 0; s < 3; ++s) {
    int H = HS[s], Ci = CiS[s], NCB = NCBS[s], Co = CoS[s], Cop = CopS[s];
    int wtot = 9 * NCB * Cop * 32;
    wtrans_k<<<(wtot + 255) / 256, 256, 0, stream>>>(wgt[s + 1], wt2, Ci, Co, NCB, Cop);
    int tot = NB * H * WD;
    maskscale_k<<<(tot + 255) / 256, 256, 0, stream>>>(mIn[s], scaleB, mnextB, H,
                                                       (float)Ci);
    zero_k<<<(2 * Co + 255) / 256, 256, 0, stream>>>(sums, 2 * Co);
    convmfma_k<<<dim3(Cop / 128, NB * (H / 4)), 256, 79872, stream>>>(
        xin[s], wt2, bias[s + 1], scaleB, mnextB, bufY, sums, H, NCB, Co, Cop);
    bnfin_k<<<(Co + 63) / 64, 64, 0, stream>>>(sums, gam[s + 1], bet[s + 1], bnab, Co,
                                               1.0f / (NB * (float)H * WD));
    if (s < 2) {
      maskpool_k<<<(NB * (H / 2) * WD + 255) / 256, 256, 0, stream>>>(mnextB, mOut[s], H);
      int totp = NB * (H / 2) * WD * (Co / 8);
      bnpool_k<<<(totp + 255) / 256, 256, 0, stream>>>(bufY, bnab, mOut[s], xout[s], Co,
                                                       NCBS[s + 1 < 3 ? s + 1 : 2], H);
    } else {
      bnfeat_k<<<dim3(16, 5, 16), 128, 0, stream>>>(bufY, bnab, feat);
    }
  }

  fc1_k<<<16, 256, 0, stream>>>(feat, fw1, fb1, z1);
  fc2h_k<<<16, 128, 0, stream>>>(z1, fw2, fb2, hw, hb, (float*)d_out);
}

// Round 12
// 1418.394 us; speedup vs baseline: 3.6524x; 3.6524x over previous
//
#include <hip/hip_runtime.h>
#include <math.h>

#define NB 16
#define WD 128

typedef __bf16 bf16_t;
typedef __bf16 bf16x8 __attribute__((ext_vector_type(8)));
typedef __bf16 bf16x4 __attribute__((ext_vector_type(4)));
typedef float f32x4 __attribute__((ext_vector_type(4)));

// ---------------- zero helper ----------------
__global__ void zero_k(float* __restrict__ p, int n) {
  int i = blockIdx.x * 256 + threadIdx.x;
  if (i < n) p[i] = 0.f;
}

// ---------------- split input into data / clipped mask ----------------
__global__ void split_k(const float* __restrict__ x, float* __restrict__ data,
                        float* __restrict__ mask) {
  const int HW = 256 * 128;
  int i = blockIdx.x * 256 + threadIdx.x;
  if (i >= NB * HW) return;
  int n = i / HW, rem = i % HW;
  data[i] = x[(size_t)(n * 2) * HW + rem];
  float mv = x[(size_t)(n * 2 + 1) * HW + rem];
  mask[i] = fminf(fmaxf(mv, 0.f), 1.f);
}

// ---------------- mask 3x3 sum (pad=1) -> scale + mask_next ----------------
__global__ void maskscale_k(const float* __restrict__ m, float* __restrict__ scale,
                            float* __restrict__ mnext, int H, float Ci) {
  int i = blockIdx.x * 256 + threadIdx.x;
  int tot = NB * H * WD;
  if (i >= tot) return;
  int x = i % WD;
  int t = i / WD;
  int y = t % H;
  int n = t / H;
  const float* mn_ = m + (size_t)n * H * WD;
  float s = 0.f;
#pragma unroll
  for (int dy = -1; dy <= 1; dy++) {
    int yy = y + dy;
#pragma unroll
    for (int dx = -1; dx <= 1; dx++) {
      int xx = x + dx;
      float v = 1.0f;
      if (yy >= 0 && yy < H && xx >= 0 && xx < WD) v = mn_[yy * WD + xx];
      s += v;
    }
  }
  float valid = Ci * s;
  float sc = (9.0f * Ci) / fmaxf(valid, 1.0f);
  scale[i] = sc;
  mnext[i] = (valid <= 0.0f) ? 0.f : 1.f;
}

// ---------------- mask (2,1) maxpool ----------------
__global__ void maskpool_k(const float* __restrict__ mn, float* __restrict__ mp, int H) {
  int Hp = H / 2;
  int i = blockIdx.x * 256 + threadIdx.x;
  int tot = NB * Hp * WD;
  if (i >= tot) return;
  int x = i % WD;
  int t = i / WD;
  int yo = t % Hp;
  int n = t / Hp;
  mp[i] = fmaxf(mn[((size_t)n * H + 2 * yo) * WD + x],
                mn[((size_t)n * H + 2 * yo + 1) * WD + x]);
}

// ---------------- stage-1 direct conv (Ci=1), NHWC bf16 out ----------------
__global__ void pconv1_k(const float* __restrict__ data, const float* __restrict__ mask,
                         const float* __restrict__ w, const float* __restrict__ b,
                         const float* __restrict__ scale, const float* __restrict__ mnext,
                         bf16_t* __restrict__ y) {
  __shared__ float ws[720];
  __shared__ float bs[80];
  for (int i = threadIdx.x; i < 720; i += 256) ws[i] = w[i];
  if (threadIdx.x < 80) bs[threadIdx.x] = b[threadIdx.x];
  __syncthreads();
  const int H = 256;
  int p = blockIdx.x * 256 + threadIdx.x;
  int x = p % WD;
  int t = p / WD;
  int yy = t % H;
  int n = t / H;
  const float* dn = data + (size_t)n * H * WD;
  const float* mn = mask + (size_t)n * H * WD;
  float v[9];
#pragma unroll
  for (int dy = 0; dy < 3; dy++) {
    int yv = yy - 1 + dy;
#pragma unroll
    for (int dx = 0; dx < 3; dx++) {
      int xv = x - 1 + dx;
      float u = 0.f;
      if (yv >= 0 && yv < H && xv >= 0 && xv < WD)
        u = dn[yv * WD + xv] * mn[yv * WD + xv];
      v[dy * 3 + dx] = u;
    }
  }
  float sc = scale[p], mx = mnext[p];
  bf16_t* yp = y + (size_t)p * 80;
#pragma unroll
  for (int c8 = 0; c8 < 10; ++c8) {
    bf16x8 o;
#pragma unroll
    for (int j = 0; j < 8; ++j) {
      int co = c8 * 8 + j;
      float s = 0.f;
#pragma unroll
      for (int tt = 0; tt < 9; ++tt) s += ws[co * 9 + tt] * v[tt];
      o[j] = (bf16_t)((s * sc + bs[co]) * mx);
    }
    *(bf16x8*)(yp + c8 * 8) = o;
  }
}

// ---------------- BN stats over NHWC bf16 (stage 1) ----------------
__global__ void bnstats_k(const bf16_t* __restrict__ y, float* __restrict__ sums,
                          int C, int P) {
  int c = threadIdx.x;  // blockDim 128
  if (c >= C) return;
  float s = 0.f, q = 0.f;
  for (int p = blockIdx.x; p < P; p += gridDim.x) {
    float v = (float)y[(size_t)p * C + c];
    s += v;
    q += v * v;
  }
  atomicAdd(&sums[c], s);
  atomicAdd(&sums[C + c], q);
}

// ---------------- weight transform: w[co][ci][3][3] fp32 -> wt2 bf16 ----------------
// wt2 index: (((tap*NCB + cb)*4 + g)*Co_pad + co)*8 + j   (ci = cb*32 + g*8 + j)
__global__ void wtrans_k(const float* __restrict__ w, bf16_t* __restrict__ wt2,
                         int Ci, int Co, int NCB, int Co_pad) {
  int idx = blockIdx.x * 256 + threadIdx.x;
  int total = 9 * NCB * Co_pad * 32;
  if (idx >= total) return;
  int j = idx & 7;
  int rest = idx >> 3;
  int co = rest % Co_pad;
  int rest2 = rest / Co_pad;
  int g = rest2 & 3;
  int rest3 = rest2 >> 2;
  int cb = rest3 % NCB;
  int tap = rest3 / NCB;
  int ci = cb * 32 + g * 8 + j;
  float v = 0.f;
  if (co < Co && ci < Ci) v = w[((size_t)co * Ci + ci) * 9 + tap];
  wt2[idx] = (bf16_t)v;
}

// ---------------- MFMA implicit-GEMM 3x3 conv (stages 2-4) ----------------
// Round-12: 512-thread block (8 waves = 2 co-halves x 4 rows); each wave keeps
// r10's spill-free acc[4][8] (128 VGPRs). ALL 9 A taps (72KB) + 6 B rows
// (54KB) staged once per cb -> ONE barrier pair per cb, 288 MFMA/wave per
// drain (3x r10). Dynamic LDS 126KB -> 1 block/CU = 2 waves/SIMD.
// r11's spill lesson: scale waves/block, never acc/wave past 128.
__global__ __launch_bounds__(512, 2) void convmfma_k(
    const bf16_t* __restrict__ xmT, const bf16_t* __restrict__ wt2,
    const float* __restrict__ bias, const float* __restrict__ scale,
    const float* __restrict__ mnext, bf16_t* __restrict__ y,
    float* __restrict__ sums, int H, int NCB, int Co, int Co_pad) {
  extern __shared__ __align__(16) bf16_t smem[];
  bf16_t* Bb = smem;           // 27648 elems: 6 input rows x 9 chunks
  bf16_t* Ab = smem + 27648;   // 36864 elems: 9 taps x [g][co128][8]
  const int tid = threadIdx.x;
  const int lane = tid & 63;
  const int wave = tid >> 6;   // 0..7
  const int wm = wave & 1;     // co half
  const int wr = wave >> 1;    // output row 0..3
  const int g = lane >> 4;     // k-group of 8
  const int ln = lane & 15;    // frag row/col
  const int coTile = blockIdx.x * 128;
  const int Hq = H >> 2;
  const int bx = blockIdx.y;  // n*Hq + yquad
  const int n = bx / Hq, y0 = (bx % Hq) * 4;

  f32x4 acc[4][8];
#pragma unroll
  for (int mf = 0; mf < 4; mf++)
#pragma unroll
    for (int nf = 0; nf < 8; nf++) acc[mf][nf] = (f32x4)(0.f);

  const size_t cbStride = 4608;  // elems per (row, cb) slice
  const size_t rowStrideG = (size_t)NCB * cbStride;
  // padded row p holds input row p-1; outputs y0..y0+3 need padded y0..y0+5
  const size_t gRow0 = ((size_t)n * (H + 2) + y0) * rowStrideG;
  const size_t laneOff = (size_t)lane * 8;  // identity: lane L -> L*16B

  for (int cb = 0; cb < NCB; ++cb) {
    __syncthreads();  // previous cb's LDS reads done
    // stage B (54 chunks: 6 rows x 9) + A (72 chunks: 9 taps x 8) = 126
    const bf16_t* bsrc = xmT + gRow0 + (size_t)cb * cbStride;
    for (int c = wave; c < 126; c += 8) {
      if (c < 54) {
        int row = c / 9, chk = c - row * 9;
        __builtin_amdgcn_global_load_lds(
            (const __attribute__((address_space(1))) void*)(
                bsrc + (size_t)row * rowStrideG + chk * 512 + laneOff),
            (__attribute__((address_space(3))) void*)(&Bb[c * 512]), 16, 0, 0);
      } else {
        int t = c - 54;
        int tap = t >> 3, cc = t & 7;
        const bf16_t* asrc =
            wt2 + ((((size_t)tap * NCB + cb) * 4 + (cc >> 1)) * Co_pad + coTile +
                   (cc & 1) * 64) * 8;
        __builtin_amdgcn_global_load_lds(
            (const __attribute__((address_space(1))) void*)(asrc + laneOff),
            (__attribute__((address_space(3))) void*)(&Ab[t * 512]), 16, 0, 0);
      }
    }
    __syncthreads();  // staging visible

#pragma unroll
    for (int dy = 0; dy < 3; ++dy) {
      const bf16_t* brow = Bb + (size_t)(wr + dy) * 4608;
#pragma unroll
      for (int dx = 0; dx < 3; ++dx) {
        const int tap = dy * 3 + dx;
        bf16x8 a[4];
#pragma unroll
        for (int mf = 0; mf < 4; ++mf)
          a[mf] = *(const bf16x8*)(Ab + tap * 4096 +
                                   (g * 128 + wm * 64 + mf * 16 + ln) * 8);
#pragma unroll
        for (int nf = 0; nf < 8; ++nf) {
          int colx = nf * 16 + ln + dx;
          bf16x8 b =
              *(const bf16x8*)(brow + ((colx >> 4) * 4 + g) * 128 + (colx & 15) * 8);
#pragma unroll
          for (int mf = 0; mf < 4; ++mf)
            acc[mf][nf] =
                __builtin_amdgcn_mfma_f32_16x16x32_bf16(a[mf], b, acc[mf][nf], 0, 0, 0);
        }
      }
    }
  }

  // epilogue: partial-conv scale + bias + mask, write NHWC bf16, BN stats
  const int yrow = y0 + wr;
  const int pixBase = (n * H + yrow) * WD;
  float scl[8], msk[8];
#pragma unroll
  for (int nf = 0; nf < 8; ++nf) {
    int x = nf * 16 + ln;
    scl[nf] = scale[pixBase + x];
    msk[nf] = mnext[pixBase + x];
  }
#pragma unroll
  for (int mf = 0; mf < 4; ++mf) {
    if (coTile + wm * 64 + mf * 16 >= Co) continue;  // padded frag
    int coB = coTile + wm * 64 + mf * 16 + g * 4;
    f32x4 bias4 = *(const f32x4*)&bias[coB];
    f32x4 s4 = (f32x4)(0.f), q4 = (f32x4)(0.f);
#pragma unroll
    for (int nf = 0; nf < 8; ++nf) {
      int x = nf * 16 + ln;
      f32x4 v;
      bf16x4 o;
#pragma unroll
      for (int r = 0; r < 4; ++r) {
        v[r] = (acc[mf][nf][r] * scl[nf] + bias4[r]) * msk[nf];
        o[r] = (bf16_t)v[r];
      }
      *(bf16x4*)&y[(size_t)(pixBase + x) * Co + coB] = o;
      s4 += v;
      q4 += v * v;
    }
#pragma unroll
    for (int off = 1; off < 16; off <<= 1) {
#pragma unroll
      for (int r = 0; r < 4; ++r) {
        float ts = s4[r], tq = q4[r];
        s4[r] = ts + __shfl_xor(ts, off);
        q4[r] = tq + __shfl_xor(tq, off);
      }
    }
    if (ln == 0) {
#pragma unroll
      for (int r = 0; r < 4; ++r) {
        atomicAdd(&sums[coB + r], s4[r]);
        atomicAdd(&sums[Co + coB + r], q4[r]);
      }
    }
  }
}

// ---------------- BN finalize ----------------
__global__ void bnfin_k(const float* __restrict__ sums, const float* __restrict__ g,
                        const float* __restrict__ be, float* __restrict__ ab, int Co,
                        float invCount) {
  int c = blockIdx.x * 64 + threadIdx.x;
  if (c >= Co) return;
  float mean = sums[c] * invCount;
  float var = sums[Co + c] * invCount - mean * mean;
  float rs = rsqrtf(var + 1e-5f);
  float a = g[c] * rs;
  ab[c] = a;
  ab[Co + c] = be[c] - mean * a;
}

// ---------------- BN + ReLU + (2,1) pool + mask -> chunked padded xmT ----------------
// out layout: [n][Hp+2][NCBn][9 chunks][g][col16][8]
__global__ void bnpool_k(const bf16_t* __restrict__ y, const float* __restrict__ ab,
                         const float* __restrict__ mp, bf16_t* __restrict__ out, int C,
                         int NCBn, int H) {
  int Hp = H / 2;
  int Cq = C / 8;
  int tid = blockIdx.x * 256 + threadIdx.x;
  int total = NB * Hp * WD * Cq;
  if (tid >= total) return;
  int c8 = tid % Cq;
  int t = tid / Cq;
  int x = t % WD;
  t /= WD;
  int yo = t % Hp;
  int n = t / Hp;
  int c = c8 * 8;
  const bf16_t* p0 = y + ((size_t)((n * H + 2 * yo) * WD + x)) * C + c;
  const bf16_t* p1 = p0 + (size_t)WD * C;
  float mpv = mp[(n * Hp + yo) * WD + x];
  bf16x8 v0 = *(const bf16x8*)p0;
  bf16x8 v1 = *(const bf16x8*)p1;
  bf16x8 o;
#pragma unroll
  for (int j = 0; j < 8; ++j) {
    float a = ab[c + j], sh = ab[C + c + j];
    float f0 = (float)v0[j] * a + sh;
    float f1 = (float)v1[j] * a + sh;
    o[j] = (bf16_t)(fmaxf(fmaxf(f0, f1), 0.f) * mpv);
  }
  int cb = c >> 5;           // 32-ci block
  int gg = (c & 31) >> 3;    // k-group within block
  int col = x + 1;           // stored col (1..128)
  int chk = col >> 4, lcol = col & 15;
  *(bf16x8*)&out[((((size_t)n * (Hp + 2) + yo + 1) * NCBn + cb) * 9 + chk) * 512 +
                 gg * 128 + lcol * 8] = o;
}

// ---------------- stage-4: BN + ReLU + pool + global mean -> feat ----------------
__global__ void bnfeat_k(const bf16_t* __restrict__ y, const float* __restrict__ ab,
                         float* __restrict__ feat) {
  int n = blockIdx.x, cc = blockIdx.y, yo = blockIdx.z;
  int c = cc * 128 + threadIdx.x;  // C = 640
  float a = ab[c], sh = ab[640 + c];
  float s = 0.f;
  for (int x = 0; x < WD; ++x) {
    size_t p0 = ((size_t)(n * 32 + 2 * yo) * WD + x) * 640 + c;
    float v0 = (float)y[p0] * a + sh;
    float v1 = (float)y[p0 + (size_t)WD * 640] * a + sh;
    s += fmaxf(fmaxf(v0, v1), 0.f);
  }
  atomicAdd(&feat[n * 640 + c], s * (1.f / 2048.f));
}

// ---------------- fc1 (640->256) + relu ----------------
__global__ void fc1_k(const float* __restrict__ feat, const float* __restrict__ fw,
                      const float* __restrict__ fb, float* __restrict__ z1) {
  int n = blockIdx.x;
  int o = threadIdx.x;
  const float* f = feat + n * 640;
  const float* wr = fw + o * 640;
  float s = fb[o];
  for (int k = 0; k < 640; k++) s += f[k] * wr[k];
  z1[n * 256 + o] = fmaxf(s, 0.f);
}

// ---------------- fc2 (256->128) + relu + head + sigmoid ----------------
__global__ void fc2h_k(const float* __restrict__ z1, const float* __restrict__ fw2,
                       const float* __restrict__ fb2, const float* __restrict__ hw,
                       const float* __restrict__ hb, float* __restrict__ out) {
  int n = blockIdx.x;
  int o = threadIdx.x;
  const float* zr = z1 + n * 256;
  const float* wr = fw2 + o * 256;
  float s = fb2[o];
  for (int k = 0; k < 256; k++) s += zr[k] * wr[k];
  s = fmaxf(s, 0.f) * hw[o];
#pragma unroll
  for (int off = 32; off >= 1; off >>= 1) s += __shfl_down(s, off, 64);
  __shared__ float red[2];
  if ((threadIdx.x & 63) == 0) red[threadIdx.x >> 6] = s;
  __syncthreads();
  if (threadIdx.x == 0) {
    float t = red[0] + red[1] + hb[0];
    out[n] = 1.f / (1.f + expf(-t));
  }
}

extern "C" void kernel_launch(void* const* d_in, const int* in_sizes, int n_in,
                              void* d_out, int out_size, void* d_ws, size_t ws_size,
                              hipStream_t stream) {
  const float* x = (const float*)d_in[0];
  const float* wgt[4] = {(const float*)d_in[1], (const float*)d_in[5],
                         (const float*)d_in[9], (const float*)d_in[13]};
  const float* bias[4] = {(const float*)d_in[2], (const float*)d_in[6],
                          (const float*)d_in[10], (const float*)d_in[14]};
  const float* gam[4] = {(const float*)d_in[3], (const float*)d_in[7],
                         (const float*)d_in[11], (const float*)d_in[15]};
  const float* bet[4] = {(const float*)d_in[4], (const float*)d_in[8],
                         (const float*)d_in[12], (const float*)d_in[16]};
  const float* fw1 = (const float*)d_in[17];
  const float* fb1 = (const float*)d_in[18];
  const float* fw2 = (const float*)d_in[19];
  const float* fb2 = (const float*)d_in[20];
  const float* hw = (const float*)d_in[21];
  const float* hb = (const float*)d_in[22];

  // allow 126KB dynamic LDS for the conv kernel (host-side, capture-safe)
  static bool attrSet = false;
  if (!attrSet) {
    hipFuncSetAttribute((const void*)convmfma_k,
                        hipFuncAttributeMaxDynamicSharedMemorySize, 129024);
    attrSet = true;
  }

  char* base = (char*)d_ws;
  size_t off = 0;
  auto alloc = [&](size_t bytes) {
    char* p = base + off;
    off += (bytes + 255) & ~(size_t)255;
    return p;
  };
  bf16_t* bufY = (bf16_t*)alloc(83886080);  // 41,943,040 bf16
  const size_t xmtElems = 28786688;         // 16*130*3*4608 + 32768 slack
  bf16_t* xmT0 = (bf16_t*)alloc(xmtElems * 2);
  bf16_t* xmT1 = (bf16_t*)alloc(xmtElems * 2);
  bf16_t* wt2 = (bf16_t*)alloc(3686400);
  float* data = (float*)alloc(2097152);
  float* mask0 = (float*)alloc(2097152);
  float* mask1 = (float*)alloc(2097152);
  float* scaleB = (float*)alloc(2097152);
  float* mnextB = (float*)alloc(2097152);
  float* sums = (float*)alloc(5120);
  float* bnab = (float*)alloc(5120);
  float* feat = (float*)alloc(40960);
  float* z1 = (float*)alloc(16384);

  // zero xmT0+xmT1 (contiguous) and feat
  {
    int nf = (int)(xmtElems * 2 * 2 / 4);  // both buffers as floats
    zero_k<<<(nf + 255) / 256, 256, 0, stream>>>((float*)xmT0, nf);
    zero_k<<<40, 256, 0, stream>>>(feat, 10240);
  }

  // split input
  split_k<<<(NB * 256 * 128 + 255) / 256, 256, 0, stream>>>(x, data, mask0);

  // ---------- stage 1 (direct, Ci=1, Co=80, H=256) ----------
  {
    int H = 256;
    int tot = NB * H * WD;
    maskscale_k<<<(tot + 255) / 256, 256, 0, stream>>>(mask0, scaleB, mnextB, H, 1.0f);
    zero_k<<<1, 256, 0, stream>>>(sums, 160);
    pconv1_k<<<tot / 256, 256, 0, stream>>>(data, mask0, wgt[0], bias[0], scaleB,
                                            mnextB, bufY);
    bnstats_k<<<512, 128, 0, stream>>>(bufY, sums, 80, NB * H * WD);
    bnfin_k<<<2, 64, 0, stream>>>(sums, gam[0], bet[0], bnab, 80,
                                  1.0f / (NB * (float)H * WD));
    maskpool_k<<<(NB * (H / 2) * WD + 255) / 256, 256, 0, stream>>>(mnextB, mask1, H);
    int totp = NB * (H / 2) * WD * (80 / 8);
    bnpool_k<<<(totp + 255) / 256, 256, 0, stream>>>(bufY, bnab, mask1, xmT0, 80, 3, H);
  }

  // ---------- stages 2-4 (MFMA implicit GEMM) ----------
  const int CiS[3] = {80, 160, 320};
  const int NCBS[3] = {3, 5, 10};
  const int CoS[3] = {160, 320, 640};
  const int CopS[3] = {256, 384, 640};
  const int HS[3] = {128, 64, 32};
  bf16_t* xin[3] = {xmT0, xmT1, xmT0};
  bf16_t* xout[3] = {xmT1, xmT0, nullptr};
  float* mIn[3] = {mask1, mask0, mask1};
  float* mOut[3] = {mask0, mask1, nullptr};

  for (int s = 0; s < 3; ++s) {
    int H = HS[s], Ci = CiS[s], NCB = NCBS[s], Co = CoS[s], Cop = CopS[s];
    int wtot = 9 * NCB * Cop * 32;
    wtrans_k<<<(wtot + 255) / 256, 256, 0, stream>>>(wgt[s + 1], wt2, Ci, Co, NCB, Cop);
    int tot = NB * H * WD;
    maskscale_k<<<(tot + 255) / 256, 256, 0, stream>>>(mIn[s], scaleB, mnextB, H,
                                                       (float)Ci);
    zero_k<<<(2 * Co + 255) / 256, 256, 0, stream>>>(sums, 2 * Co);
    convmfma_k<<<dim3(Cop / 128, NB * (H / 4)), 512, 129024, stream>>>(
        xin[s], wt2, bias[s + 1], scaleB, mnextB, bufY, sums, H, NCB, Co, Cop);
    bnfin_k<<<(Co + 63) / 64, 64, 0, stream>>>(sums, gam[s + 1], bet[s + 1], bnab, Co,
                                               1.0f / (NB * (float)H * WD));
    if (s < 2) {
      maskpool_k<<<(NB * (H / 2) * WD + 255) / 256, 256, 0, stream>>>(mnextB, mOut[s], H);
      int totp = NB * (H / 2) * WD * (Co / 8);
      bnpool_k<<<(totp + 255) / 256, 256, 0, stream>>>(bufY, bnab, mOut[s], xout[s], Co,
                                                       NCBS[s + 1 < 3 ? s + 1 : 2], H);
    } else {
      bnfeat_k<<<dim3(16, 5, 16), 128, 0, stream>>>(bufY, bnab, feat);
    }
  }

  fc1_k<<<16, 256, 0, stream>>>(feat, fw1, fb1, z1);
  fc2h_k<<<16, 128, 0, stream>>>(z1, fw2, fb2, hw, hb, (float*)d_out);
}

// Round 13
// 1039.778 us; speedup vs baseline: 4.9823x; 1.3641x over previous
//
#include <hip/hip_runtime.h>
#include <math.h>

#define NB 16
#define WD 128

typedef __bf16 bf16_t;
typedef __bf16 bf16x8 __attribute__((ext_vector_type(8)));
typedef __bf16 bf16x4 __attribute__((ext_vector_type(4)));
typedef float f32x4 __attribute__((ext_vector_type(4)));

// ---------------- zero helper ----------------
__global__ void zero_k(float* __restrict__ p, int n) {
  int i = blockIdx.x * 256 + threadIdx.x;
  if (i < n) p[i] = 0.f;
}

// ---------------- split input into data / clipped mask ----------------
__global__ void split_k(const float* __restrict__ x, float* __restrict__ data,
                        float* __restrict__ mask) {
  const int HW = 256 * 128;
  int i = blockIdx.x * 256 + threadIdx.x;
  if (i >= NB * HW) return;
  int n = i / HW, rem = i % HW;
  data[i] = x[(size_t)(n * 2) * HW + rem];
  float mv = x[(size_t)(n * 2 + 1) * HW + rem];
  mask[i] = fminf(fmaxf(mv, 0.f), 1.f);
}

// ---------------- mask 3x3 sum (pad=1) -> scale + mask_next ----------------
__global__ void maskscale_k(const float* __restrict__ m, float* __restrict__ scale,
                            float* __restrict__ mnext, int H, float Ci) {
  int i = blockIdx.x * 256 + threadIdx.x;
  int tot = NB * H * WD;
  if (i >= tot) return;
  int x = i % WD;
  int t = i / WD;
  int y = t % H;
  int n = t / H;
  const float* mn_ = m + (size_t)n * H * WD;
  float s = 0.f;
#pragma unroll
  for (int dy = -1; dy <= 1; dy++) {
    int yy = y + dy;
#pragma unroll
    for (int dx = -1; dx <= 1; dx++) {
      int xx = x + dx;
      float v = 1.0f;
      if (yy >= 0 && yy < H && xx >= 0 && xx < WD) v = mn_[yy * WD + xx];
      s += v;
    }
  }
  float valid = Ci * s;
  float sc = (9.0f * Ci) / fmaxf(valid, 1.0f);
  scale[i] = sc;
  mnext[i] = (valid <= 0.0f) ? 0.f : 1.f;
}

// ---------------- mask (2,1) maxpool ----------------
__global__ void maskpool_k(const float* __restrict__ mn, float* __restrict__ mp, int H) {
  int Hp = H / 2;
  int i = blockIdx.x * 256 + threadIdx.x;
  int tot = NB * Hp * WD;
  if (i >= tot) return;
  int x = i % WD;
  int t = i / WD;
  int yo = t % Hp;
  int n = t / Hp;
  mp[i] = fmaxf(mn[((size_t)n * H + 2 * yo) * WD + x],
                mn[((size_t)n * H + 2 * yo + 1) * WD + x]);
}

// ---------------- stage-1 direct conv (Ci=1), NHWC bf16 out ----------------
__global__ void pconv1_k(const float* __restrict__ data, const float* __restrict__ mask,
                         const float* __restrict__ w, const float* __restrict__ b,
                         const float* __restrict__ scale, const float* __restrict__ mnext,
                         bf16_t* __restrict__ y) {
  __shared__ float ws[720];
  __shared__ float bs[80];
  for (int i = threadIdx.x; i < 720; i += 256) ws[i] = w[i];
  if (threadIdx.x < 80) bs[threadIdx.x] = b[threadIdx.x];
  __syncthreads();
  const int H = 256;
  int p = blockIdx.x * 256 + threadIdx.x;
  int x = p % WD;
  int t = p / WD;
  int yy = t % H;
  int n = t / H;
  const float* dn = data + (size_t)n * H * WD;
  const float* mn = mask + (size_t)n * H * WD;
  float v[9];
#pragma unroll
  for (int dy = 0; dy < 3; dy++) {
    int yv = yy - 1 + dy;
#pragma unroll
    for (int dx = 0; dx < 3; dx++) {
      int xv = x - 1 + dx;
      float u = 0.f;
      if (yv >= 0 && yv < H && xv >= 0 && xv < WD)
        u = dn[yv * WD + xv] * mn[yv * WD + xv];
      v[dy * 3 + dx] = u;
    }
  }
  float sc = scale[p], mx = mnext[p];
  bf16_t* yp = y + (size_t)p * 80;
#pragma unroll
  for (int c8 = 0; c8 < 10; ++c8) {
    bf16x8 o;
#pragma unroll
    for (int j = 0; j < 8; ++j) {
      int co = c8 * 8 + j;
      float s = 0.f;
#pragma unroll
      for (int tt = 0; tt < 9; ++tt) s += ws[co * 9 + tt] * v[tt];
      o[j] = (bf16_t)((s * sc + bs[co]) * mx);
    }
    *(bf16x8*)(yp + c8 * 8) = o;
  }
}

// ---------------- BN stats over NHWC bf16 (stage 1, C=80) ----------------
// Coalesced + vectorized: block 320 threads, thread owns channel-group
// tid%10 (stride 320 chunks keeps it constant), bf16x8 loads (5KB contiguous
// per block-iteration), LDS tree reduce -> 1 atomic per channel per block.
// Replaces the 305us scalar-strided version (275 GB/s -> ~5 TB/s).
__global__ __launch_bounds__(320) void bnstats2_k(const bf16_t* __restrict__ y,
                                                  float* __restrict__ sums) {
  const int ITER = 16;
  const int tid = threadIdx.x;
  float s[8], q[8];
#pragma unroll
  for (int j = 0; j < 8; ++j) { s[j] = 0.f; q[j] = 0.f; }
  size_t base = (size_t)blockIdx.x * 320 * ITER;
  for (int k = 0; k < ITER; ++k) {
    size_t chunk = base + (size_t)k * 320 + tid;
    bf16x8 v = *(const bf16x8*)(y + chunk * 8);
#pragma unroll
    for (int j = 0; j < 8; ++j) {
      float f = (float)v[j];
      s[j] += f;
      q[j] += f * f;
    }
  }
  __shared__ float red[320][8];
#pragma unroll
  for (int j = 0; j < 8; ++j) red[tid][j] = s[j];
  __syncthreads();
  float ssum = 0.f;
  if (tid < 80) {
    int c8 = tid >> 3, j = tid & 7;
    for (int i = 0; i < 32; ++i) ssum += red[c8 + 10 * i][j];
  }
  __syncthreads();
#pragma unroll
  for (int j = 0; j < 8; ++j) red[tid][j] = q[j];
  __syncthreads();
  if (tid < 80) {
    int c8 = tid >> 3, j = tid & 7;
    float qsum = 0.f;
    for (int i = 0; i < 32; ++i) qsum += red[c8 + 10 * i][j];
    atomicAdd(&sums[tid], ssum);
    atomicAdd(&sums[80 + tid], qsum);
  }
}

// ---------------- weight transform: w[co][ci][3][3] fp32 -> wt2 bf16 ----------------
// wt2 index: (((tap*NCB + cb)*4 + g)*Co_pad + co)*8 + j   (ci = cb*32 + g*8 + j)
__global__ void wtrans_k(const float* __restrict__ w, bf16_t* __restrict__ wt2,
                         int Ci, int Co, int NCB, int Co_pad) {
  int idx = blockIdx.x * 256 + threadIdx.x;
  int total = 9 * NCB * Co_pad * 32;
  if (idx >= total) return;
  int j = idx & 7;
  int rest = idx >> 3;
  int co = rest % Co_pad;
  int rest2 = rest / Co_pad;
  int g = rest2 & 3;
  int rest3 = rest2 >> 2;
  int cb = rest3 % NCB;
  int tap = rest3 / NCB;
  int ci = cb * 32 + g * 8 + j;
  float v = 0.f;
  if (co < Co && ci < Ci) v = w[((size_t)co * Ci + ci) * 9 + tap];
  wt2[idx] = (bf16_t)v;
}

// ---------------- MFMA implicit-GEMM 3x3 conv (stages 2-4) ----------------
// Round-10 config (session best): 128 co x 256 px (2 output rows) per block,
// wave tile 64co x 128px, acc[4][8]. Per (cb,dy) event: A 24KB (3 dx taps)
// [+ B 36KB (4 input rows) when dy==0]; 96 MFMA/wave/event. Static LDS 60KB,
// launch_bounds(256,2) -> 2 blocks/CU. r11/r12 lessons: never push acc past
// 128/wave (spill -> 8.7GB scratch traffic); 1 block/CU loses all overlap.
__global__ __launch_bounds__(256, 2) void convmfma_k(
    const bf16_t* __restrict__ xmT, const bf16_t* __restrict__ wt2,
    const float* __restrict__ bias, const float* __restrict__ scale,
    const float* __restrict__ mnext, bf16_t* __restrict__ y,
    float* __restrict__ sums, int H, int NCB, int Co, int Co_pad) {
  __shared__ bf16_t Ab[3][4096];  // 24KB: 3 dx taps x [g][co128][8]
  __shared__ bf16_t Bb[4][4608];  // 36KB: 4 input rows x 9 chunks
  const int tid = threadIdx.x;
  const int lane = tid & 63;
  const int wave = tid >> 6;
  const int wm = wave >> 1;  // co half
  const int wn = wave & 1;   // output row within pair
  const int g = lane >> 4;   // k-group of 8
  const int ln = lane & 15;  // frag row/col
  const int coTile = blockIdx.x * 128;
  const int Hh = H >> 1;
  const int bx = blockIdx.y;  // n*Hh + ypair
  const int n = bx / Hh, y0 = (bx % Hh) * 2;

  f32x4 acc[4][8];
#pragma unroll
  for (int mf = 0; mf < 4; mf++)
#pragma unroll
    for (int nf = 0; nf < 8; nf++) acc[mf][nf] = (f32x4)(0.f);

  const size_t cbStride = 4608;  // elems per (row, cb) slice
  const size_t rowStrideG = (size_t)NCB * cbStride;
  // padded row index y0 corresponds to input row y0-1
  const size_t gRow0 = ((size_t)n * (H + 2) + y0) * rowStrideG;
  const size_t laneOff = (size_t)lane * 8;  // identity: lane L -> L*16B

  for (int cb = 0; cb < NCB; ++cb) {
#pragma unroll
    for (int dy = 0; dy < 3; ++dy) {
      __syncthreads();  // previous event's LDS reads done
      if (dy == 0) {
        // stage B: 4 input rows (y0-1 .. y0+2) of this cb, 36 chunks
        const bf16_t* bsrc = xmT + gRow0 + (size_t)cb * cbStride;
        for (int c = wave; c < 36; c += 4) {
          int row = c / 9, chk = c - row * 9;
          __builtin_amdgcn_global_load_lds(
              (const __attribute__((address_space(1))) void*)(
                  bsrc + (size_t)row * rowStrideG + chk * 512 + laneOff),
              (__attribute__((address_space(3))) void*)(&Bb[row][chk * 512]), 16, 0, 0);
        }
      }
      // stage A: taps dy*3+{0,1,2}, 24 chunks
      for (int c = wave; c < 24; c += 4) {
        int tl = c >> 3, cc = c & 7;
        int tap = dy * 3 + tl;
        const bf16_t* asrc =
            wt2 + ((((size_t)tap * NCB + cb) * 4 + (cc >> 1)) * Co_pad + coTile +
                   (cc & 1) * 64) * 8;
        __builtin_amdgcn_global_load_lds(
            (const __attribute__((address_space(1))) void*)(asrc + laneOff),
            (__attribute__((address_space(3))) void*)(&Ab[tl][cc * 512]), 16, 0, 0);
      }
      __syncthreads();  // staging visible

      const bf16_t* brow = &Bb[wn + dy][0];
#pragma unroll
      for (int dx = 0; dx < 3; ++dx) {
        bf16x8 a[4];
#pragma unroll
        for (int mf = 0; mf < 4; ++mf)
          a[mf] = *(const bf16x8*)(Ab[dx] + (g * 128 + wm * 64 + mf * 16 + ln) * 8);
#pragma unroll
        for (int nf = 0; nf < 8; ++nf) {
          int colx = nf * 16 + ln + dx;
          bf16x8 b =
              *(const bf16x8*)(brow + ((colx >> 4) * 4 + g) * 128 + (colx & 15) * 8);
#pragma unroll
          for (int mf = 0; mf < 4; ++mf)
            acc[mf][nf] =
                __builtin_amdgcn_mfma_f32_16x16x32_bf16(a[mf], b, acc[mf][nf], 0, 0, 0);
        }
      }
    }
  }

  // epilogue: partial-conv scale + bias + mask, write NHWC bf16, BN stats
  const int yrow = y0 + wn;
  const int pixBase = (n * H + yrow) * WD;
  float scl[8], msk[8];
#pragma unroll
  for (int nf = 0; nf < 8; ++nf) {
    int x = nf * 16 + ln;
    scl[nf] = scale[pixBase + x];
    msk[nf] = mnext[pixBase + x];
  }
#pragma unroll
  for (int mf = 0; mf < 4; ++mf) {
    if (coTile + wm * 64 + mf * 16 >= Co) continue;  // padded frag
    int coB = coTile + wm * 64 + mf * 16 + g * 4;
    f32x4 bias4 = *(const f32x4*)&bias[coB];
    f32x4 s4 = (f32x4)(0.f), q4 = (f32x4)(0.f);
#pragma unroll
    for (int nf = 0; nf < 8; ++nf) {
      int x = nf * 16 + ln;
      f32x4 v;
      bf16x4 o;
#pragma unroll
      for (int r = 0; r < 4; ++r) {
        v[r] = (acc[mf][nf][r] * scl[nf] + bias4[r]) * msk[nf];
        o[r] = (bf16_t)v[r];
      }
      *(bf16x4*)&y[(size_t)(pixBase + x) * Co + coB] = o;
      s4 += v;
      q4 += v * v;
    }
#pragma unroll
    for (int off = 1; off < 16; off <<= 1) {
#pragma unroll
      for (int r = 0; r < 4; ++r) {
        float ts = s4[r], tq = q4[r];
        s4[r] = ts + __shfl_xor(ts, off);
        q4[r] = tq + __shfl_xor(tq, off);
      }
    }
    if (ln == 0) {
#pragma unroll
      for (int r = 0; r < 4; ++r) {
        atomicAdd(&sums[coB + r], s4[r]);
        atomicAdd(&sums[Co + coB + r], q4[r]);
      }
    }
  }
}

// ---------------- BN finalize ----------------
__global__ void bnfin_k(const float* __restrict__ sums, const float* __restrict__ g,
                        const float* __restrict__ be, float* __restrict__ ab, int Co,
                        float invCount) {
  int c = blockIdx.x * 64 + threadIdx.x;
  if (c >= Co) return;
  float mean = sums[c] * invCount;
  float var = sums[Co + c] * invCount - mean * mean;
  float rs = rsqrtf(var + 1e-5f);
  float a = g[c] * rs;
  ab[c] = a;
  ab[Co + c] = be[c] - mean * a;
}

// ---------------- BN + ReLU + (2,1) pool + mask -> chunked padded xmT ----------------
// out layout: [n][Hp+2][NCBn][9 chunks][g][col16][8]
__global__ void bnpool_k(const bf16_t* __restrict__ y, const float* __restrict__ ab,
                         const float* __restrict__ mp, bf16_t* __restrict__ out, int C,
                         int NCBn, int H) {
  int Hp = H / 2;
  int Cq = C / 8;
  int tid = blockIdx.x * 256 + threadIdx.x;
  int total = NB * Hp * WD * Cq;
  if (tid >= total) return;
  int c8 = tid % Cq;
  int t = tid / Cq;
  int x = t % WD;
  t /= WD;
  int yo = t % Hp;
  int n = t / Hp;
  int c = c8 * 8;
  const bf16_t* p0 = y + ((size_t)((n * H + 2 * yo) * WD + x)) * C + c;
  const bf16_t* p1 = p0 + (size_t)WD * C;
  float mpv = mp[(n * Hp + yo) * WD + x];
  bf16x8 v0 = *(const bf16x8*)p0;
  bf16x8 v1 = *(const bf16x8*)p1;
  bf16x8 o;
#pragma unroll
  for (int j = 0; j < 8; ++j) {
    float a = ab[c + j], sh = ab[C + c + j];
    float f0 = (float)v0[j] * a + sh;
    float f1 = (float)v1[j] * a + sh;
    o[j] = (bf16_t)(fmaxf(fmaxf(f0, f1), 0.f) * mpv);
  }
  int cb = c >> 5;           // 32-ci block
  int gg = (c & 31) >> 3;    // k-group within block
  int col = x + 1;           // stored col (1..128)
  int chk = col >> 4, lcol = col & 15;
  *(bf16x8*)&out[((((size_t)n * (Hp + 2) + yo + 1) * NCBn + cb) * 9 + chk) * 512 +
                 gg * 128 + lcol * 8] = o;
}

// ---------------- stage-4: BN + ReLU + pool + global mean -> feat ----------------
__global__ void bnfeat_k(const bf16_t* __restrict__ y, const float* __restrict__ ab,
                         float* __restrict__ feat) {
  int n = blockIdx.x, cc = blockIdx.y, yo = blockIdx.z;
  int c = cc * 128 + threadIdx.x;  // C = 640
  float a = ab[c], sh = ab[640 + c];
  float s = 0.f;
  for (int x = 0; x < WD; ++x) {
    size_t p0 = ((size_t)(n * 32 + 2 * yo) * WD + x) * 640 + c;
    float v0 = (float)y[p0] * a + sh;
    float v1 = (float)y[p0 + (size_t)WD * 640] * a + sh;
    s += fmaxf(fmaxf(v0, v1), 0.f);
  }
  atomicAdd(&feat[n * 640 + c], s * (1.f / 2048.f));
}

// ---------------- fc1 (640->256) + relu ----------------
__global__ void fc1_k(const float* __restrict__ feat, const float* __restrict__ fw,
                      const float* __restrict__ fb, float* __restrict__ z1) {
  int n = blockIdx.x;
  int o = threadIdx.x;
  const float* f = feat + n * 640;
  const float* wr = fw + o * 640;
  float s = fb[o];
  for (int k = 0; k < 640; k++) s += f[k] * wr[k];
  z1[n * 256 + o] = fmaxf(s, 0.f);
}

// ---------------- fc2 (256->128) + relu + head + sigmoid ----------------
__global__ void fc2h_k(const float* __restrict__ z1, const float* __restrict__ fw2,
                       const float* __restrict__ fb2, const float* __restrict__ hw,
                       const float* __restrict__ hb, float* __restrict__ out) {
  int n = blockIdx.x;
  int o = threadIdx.x;
  const float* zr = z1 + n * 256;
  const float* wr = fw2 + o * 256;
  float s = fb2[o];
  for (int k = 0; k < 256; k++) s += zr[k] * wr[k];
  s = fmaxf(s, 0.f) * hw[o];
#pragma unroll
  for (int off = 32; off >= 1; off >>= 1) s += __shfl_down(s, off, 64);
  __shared__ float red[2];
  if ((threadIdx.x & 63) == 0) red[threadIdx.x >> 6] = s;
  __syncthreads();
  if (threadIdx.x == 0) {
    float t = red[0] + red[1] + hb[0];
    out[n] = 1.f / (1.f + expf(-t));
  }
}

extern "C" void kernel_launch(void* const* d_in, const int* in_sizes, int n_in,
                              void* d_out, int out_size, void* d_ws, size_t ws_size,
                              hipStream_t stream) {
  const float* x = (const float*)d_in[0];
  const float* wgt[4] = {(const float*)d_in[1], (const float*)d_in[5],
                         (const float*)d_in[9], (const float*)d_in[13]};
  const float* bias[4] = {(const float*)d_in[2], (const float*)d_in[6],
                          (const float*)d_in[10], (const float*)d_in[14]};
  const float* gam[4] = {(const float*)d_in[3], (const float*)d_in[7],
                         (const float*)d_in[11], (const float*)d_in[15]};
  const float* bet[4] = {(const float*)d_in[4], (const float*)d_in[8],
                         (const float*)d_in[12], (const float*)d_in[16]};
  const float* fw1 = (const float*)d_in[17];
  const float* fb1 = (const float*)d_in[18];
  const float* fw2 = (const float*)d_in[19];
  const float* fb2 = (const float*)d_in[20];
  const float* hw = (const float*)d_in[21];
  const float* hb = (const float*)d_in[22];

  char* base = (char*)d_ws;
  size_t off = 0;
  auto alloc = [&](size_t bytes) {
    char* p = base + off;
    off += (bytes + 255) & ~(size_t)255;
    return p;
  };
  bf16_t* bufY = (bf16_t*)alloc(83886080);  // 41,943,040 bf16
  const size_t xmtElems = 28786688;         // 16*130*3*4608 + 32768 slack
  bf16_t* xmT0 = (bf16_t*)alloc(xmtElems * 2);
  bf16_t* xmT1 = (bf16_t*)alloc(xmtElems * 2);
  bf16_t* wt2 = (bf16_t*)alloc(3686400);
  float* data = (float*)alloc(2097152);
  float* mask0 = (float*)alloc(2097152);
  float* mask1 = (float*)alloc(2097152);
  float* scaleB = (float*)alloc(2097152);
  float* mnextB = (float*)alloc(2097152);
  float* sums = (float*)alloc(5120);
  float* bnab = (float*)alloc(5120);
  float* feat = (float*)alloc(40960);
  float* z1 = (float*)alloc(16384);

  // zero xmT0+xmT1 (contiguous) and feat
  {
    int nf = (int)(xmtElems * 2 * 2 / 4);  // both buffers as floats
    zero_k<<<(nf + 255) / 256, 256, 0, stream>>>((float*)xmT0, nf);
    zero_k<<<40, 256, 0, stream>>>(feat, 10240);
  }

  // split input
  split_k<<<(NB * 256 * 128 + 255) / 256, 256, 0, stream>>>(x, data, mask0);

  // ---------- stage 1 (direct, Ci=1, Co=80, H=256) ----------
  {
    int H = 256;
    int tot = NB * H * WD;
    maskscale_k<<<(tot + 255) / 256, 256, 0, stream>>>(mask0, scaleB, mnextB, H, 1.0f);
    zero_k<<<1, 256, 0, stream>>>(sums, 160);
    pconv1_k<<<tot / 256, 256, 0, stream>>>(data, mask0, wgt[0], bias[0], scaleB,
                                            mnextB, bufY);
    bnstats2_k<<<1024, 320, 0, stream>>>(bufY, sums);
    bnfin_k<<<2, 64, 0, stream>>>(sums, gam[0], bet[0], bnab, 80,
                                  1.0f / (NB * (float)H * WD));
    maskpool_k<<<(NB * (H / 2) * WD + 255) / 256, 256, 0, stream>>>(mnextB, mask1, H);
    int totp = NB * (H / 2) * WD * (80 / 8);
    bnpool_k<<<(totp + 255) / 256, 256, 0, stream>>>(bufY, bnab, mask1, xmT0, 80, 3, H);
  }

  // ---------- stages 2-4 (MFMA implicit GEMM) ----------
  const int CiS[3] = {80, 160, 320};
  const int NCBS[3] = {3, 5, 10};
  const int CoS[3] = {160, 320, 640};
  const int CopS[3] = {256, 384, 640};
  const int HS[3] = {128, 64, 32};
  bf16_t* xin[3] = {xmT0, xmT1, xmT0};
  bf16_t* xout[3] = {xmT1, xmT0, nullptr};
  float* mIn[3] = {mask1, mask0, mask1};
  float* mOut[3] = {mask0, mask1, nullptr};

  for (int s = 0; s < 3; ++s) {
    int H = HS[s], Ci = CiS[s], NCB = NCBS[s], Co = CoS[s], Cop = CopS[s];
    int wtot = 9 * NCB * Cop * 32;
    wtrans_k<<<(wtot + 255) / 256, 256, 0, stream>>>(wgt[s + 1], wt2, Ci, Co, NCB, Cop);
    int tot = NB * H * WD;
    maskscale_k<<<(tot + 255) / 256, 256, 0, stream>>>(mIn[s], scaleB, mnextB, H,
                                                       (float)Ci);
    zero_k<<<(2 * Co + 255) / 256, 256, 0, stream>>>(sums, 2 * Co);
    convmfma_k<<<dim3(Cop / 128, NB * (H / 2)), 256, 0, stream>>>(
        xin[s], wt2, bias[s + 1], scaleB, mnextB, bufY, sums, H, NCB, Co, Cop);
    bnfin_k<<<(Co + 63) / 64, 64, 0, stream>>>(sums, gam[s + 1], bet[s + 1], bnab, Co,
                                               1.0f / (NB * (float)H * WD));
    if (s < 2) {
      maskpool_k<<<(NB * (H / 2) * WD + 255) / 256, 256, 0, stream>>>(mnextB, mOut[s], H);
      int totp = NB * (H / 2) * WD * (Co / 8);
      bnpool_k<<<(totp + 255) / 256, 256, 0, stream>>>(bufY, bnab, mOut[s], xout[s], Co,
                                                       NCBS[s + 1 < 3 ? s + 1 : 2], H);
    } else {
      bnfeat_k<<<dim3(16, 5, 16), 128, 0, stream>>>(bufY, bnab, feat);
    }
  }

  fc1_k<<<16, 256, 0, stream>>>(feat, fw1, fb1, z1);
  fc2h_k<<<16, 128, 0, stream>>>(z1, fw2, fb2, hw, hb, (float*)d_out);
}

// Round 14
// 843.216 us; speedup vs baseline: 6.1438x; 1.2331x over previous
//
#include <hip/hip_runtime.h>
#include <math.h>

#define NB 16
#define WD 128

typedef __bf16 bf16_t;
typedef __bf16 bf16x8 __attribute__((ext_vector_type(8)));
typedef __bf16 bf16x4 __attribute__((ext_vector_type(4)));
typedef float f32x4 __attribute__((ext_vector_type(4)));

// ---------------- zero helper ----------------
__global__ void zero_k(float* __restrict__ p, int n) {
  int i = blockIdx.x * 256 + threadIdx.x;
  if (i < n) p[i] = 0.f;
}

// ---------------- border zeroing for xmT buffers ----------------
// layout: [n][Hp+2][NCB][9 chunks][512]. Only borders need zeros: padded
// rows 0 and Hp+1, plus (interior rows) stored col 0 (left pad, chunk0
// [g][0][8]) and stored col 129 (right pad, chunk8 [g][1][8]).
// Replaces a 115MB full-buffer memset (~7MB total instead).
__global__ void zrows_k(bf16_t* __restrict__ out, int Hp, int NCB) {
  int total = NB * 2 * NCB * 576;
  int i = blockIdx.x * 256 + threadIdx.x;
  if (i >= total) return;
  int e = i % 576;
  int t = i / 576;
  int cb = t % NCB;
  t /= NCB;
  int rsel = t & 1;
  int n = t >> 1;
  int row = rsel ? (Hp + 1) : 0;
  bf16x8 z = (bf16x8)(bf16_t)0.f;
  *(bf16x8*)&out[(((size_t)n * (Hp + 2) + row) * NCB + cb) * 4608 + e * 8] = z;
}
__global__ void zcols_k(bf16_t* __restrict__ out, int Hp, int NCB) {
  int total = NB * Hp * NCB * 8;
  int i = blockIdx.x * 256 + threadIdx.x;
  if (i >= total) return;
  int j = i & 7;
  int t = i >> 3;
  int cb = t % NCB;
  t /= NCB;
  int row = (t % Hp) + 1;
  int n = t / Hp;
  size_t base = (((size_t)n * (Hp + 2) + row) * NCB + cb) * 4608;
  size_t off = (j < 4) ? (size_t)(j * 128) : (size_t)(4096 + (j - 4) * 128 + 8);
  bf16x8 z = (bf16x8)(bf16_t)0.f;
  *(bf16x8*)&out[base + off] = z;
}

// ---------------- split input into data / clipped mask ----------------
__global__ void split_k(const float* __restrict__ x, float* __restrict__ data,
                        float* __restrict__ mask) {
  const int HW = 256 * 128;
  int i = blockIdx.x * 256 + threadIdx.x;
  if (i >= NB * HW) return;
  int n = i / HW, rem = i % HW;
  data[i] = x[(size_t)(n * 2) * HW + rem];
  float mv = x[(size_t)(n * 2 + 1) * HW + rem];
  mask[i] = fminf(fmaxf(mv, 0.f), 1.f);
}

// ---------------- mask 3x3 sum (pad=1) -> scale + mask_next ----------------
__global__ void maskscale_k(const float* __restrict__ m, float* __restrict__ scale,
                            float* __restrict__ mnext, int H, float Ci) {
  int i = blockIdx.x * 256 + threadIdx.x;
  int tot = NB * H * WD;
  if (i >= tot) return;
  int x = i % WD;
  int t = i / WD;
  int y = t % H;
  int n = t / H;
  const float* mn_ = m + (size_t)n * H * WD;
  float s = 0.f;
#pragma unroll
  for (int dy = -1; dy <= 1; dy++) {
    int yy = y + dy;
#pragma unroll
    for (int dx = -1; dx <= 1; dx++) {
      int xx = x + dx;
      float v = 1.0f;
      if (yy >= 0 && yy < H && xx >= 0 && xx < WD) v = mn_[yy * WD + xx];
      s += v;
    }
  }
  float valid = Ci * s;
  float sc = (9.0f * Ci) / fmaxf(valid, 1.0f);
  scale[i] = sc;
  mnext[i] = (valid <= 0.0f) ? 0.f : 1.f;
}

// ---------------- mask (2,1) maxpool ----------------
__global__ void maskpool_k(const float* __restrict__ mn, float* __restrict__ mp, int H) {
  int Hp = H / 2;
  int i = blockIdx.x * 256 + threadIdx.x;
  int tot = NB * Hp * WD;
  if (i >= tot) return;
  int x = i % WD;
  int t = i / WD;
  int yo = t % Hp;
  int n = t / Hp;
  mp[i] = fmaxf(mn[((size_t)n * H + 2 * yo) * WD + x],
                mn[((size_t)n * H + 2 * yo + 1) * WD + x]);
}

// ---------------- stage-1 direct conv (Ci=1), NHWC bf16 out ----------------
__global__ void pconv1_k(const float* __restrict__ data, const float* __restrict__ mask,
                         const float* __restrict__ w, const float* __restrict__ b,
                         const float* __restrict__ scale, const float* __restrict__ mnext,
                         bf16_t* __restrict__ y) {
  __shared__ float ws[720];
  __shared__ float bs[80];
  for (int i = threadIdx.x; i < 720; i += 256) ws[i] = w[i];
  if (threadIdx.x < 80) bs[threadIdx.x] = b[threadIdx.x];
  __syncthreads();
  const int H = 256;
  int p = blockIdx.x * 256 + threadIdx.x;
  int x = p % WD;
  int t = p / WD;
  int yy = t % H;
  int n = t / H;
  const float* dn = data + (size_t)n * H * WD;
  const float* mn = mask + (size_t)n * H * WD;
  float v[9];
#pragma unroll
  for (int dy = 0; dy < 3; dy++) {
    int yv = yy - 1 + dy;
#pragma unroll
    for (int dx = 0; dx < 3; dx++) {
      int xv = x - 1 + dx;
      float u = 0.f;
      if (yv >= 0 && yv < H && xv >= 0 && xv < WD)
        u = dn[yv * WD + xv] * mn[yv * WD + xv];
      v[dy * 3 + dx] = u;
    }
  }
  float sc = scale[p], mx = mnext[p];
  bf16_t* yp = y + (size_t)p * 80;
#pragma unroll
  for (int c8 = 0; c8 < 10; ++c8) {
    bf16x8 o;
#pragma unroll
    for (int j = 0; j < 8; ++j) {
      int co = c8 * 8 + j;
      float s = 0.f;
#pragma unroll
      for (int tt = 0; tt < 9; ++tt) s += ws[co * 9 + tt] * v[tt];
      o[j] = (bf16_t)((s * sc + bs[co]) * mx);
    }
    *(bf16x8*)(yp + c8 * 8) = o;
  }
}

// ---------------- generic BN stats over NHWC bf16 (C = nc8*8, nc8 | 320) ----------------
// Coalesced bf16x8 streaming (84MB in all stages), two-phase LDS reduce,
// <= 2*C atomics per block, grid 256. Replaces conv-epilogue atomic storm.
__global__ __launch_bounds__(320) void bnstats_g(const bf16_t* __restrict__ y,
                                                 float* __restrict__ sums, int nc8) {
  const int ITER = 64;
  const int tid = threadIdx.x;
  const int C = nc8 * 8;
  float s[8], q[8];
#pragma unroll
  for (int j = 0; j < 8; ++j) { s[j] = 0.f; q[j] = 0.f; }
  size_t base = (size_t)blockIdx.x * 320 * ITER;
  for (int k = 0; k < ITER; ++k) {
    size_t chunk = base + (size_t)k * 320 + tid;
    bf16x8 v = *(const bf16x8*)(y + chunk * 8);
#pragma unroll
    for (int j = 0; j < 8; ++j) {
      float f = (float)v[j];
      s[j] += f;
      q[j] += f * f;
    }
  }
  __shared__ float red[320][8];
  const int rows = 320 / nc8;
  float ssum[2], qsum[2];
#pragma unroll
  for (int j = 0; j < 8; ++j) red[tid][j] = s[j];
  __syncthreads();
  {
    int idx = 0;
    for (int c = tid; c < C; c += 320, ++idx) {
      int c8 = c >> 3, j = c & 7;
      float acc = 0.f;
      for (int i = 0; i < rows; ++i) acc += red[c8 + nc8 * i][j];
      ssum[idx] = acc;
    }
  }
  __syncthreads();
#pragma unroll
  for (int j = 0; j < 8; ++j) red[tid][j] = q[j];
  __syncthreads();
  {
    int idx = 0;
    for (int c = tid; c < C; c += 320, ++idx) {
      int c8 = c >> 3, j = c & 7;
      float acc = 0.f;
      for (int i = 0; i < rows; ++i) acc += red[c8 + nc8 * i][j];
      qsum[idx] = acc;
      atomicAdd(&sums[c], ssum[idx]);
      atomicAdd(&sums[C + c], qsum[idx]);
    }
  }
}

// ---------------- weight transform: w[co][ci][3][3] fp32 -> wt2 bf16 ----------------
// wt2 index: (((tap*NCB + cb)*4 + g)*Co_pad + co)*8 + j   (ci = cb*32 + g*8 + j)
__global__ void wtrans_k(const float* __restrict__ w, bf16_t* __restrict__ wt2,
                         int Ci, int Co, int NCB, int Co_pad) {
  int idx = blockIdx.x * 256 + threadIdx.x;
  int total = 9 * NCB * Co_pad * 32;
  if (idx >= total) return;
  int j = idx & 7;
  int rest = idx >> 3;
  int co = rest % Co_pad;
  int rest2 = rest / Co_pad;
  int g = rest2 & 3;
  int rest3 = rest2 >> 2;
  int cb = rest3 % NCB;
  int tap = rest3 / NCB;
  int ci = cb * 32 + g * 8 + j;
  float v = 0.f;
  if (co < Co && ci < Ci) v = w[((size_t)co * Ci + ci) * 9 + tap];
  wt2[idx] = (bf16_t)v;
}

// ---------------- MFMA implicit-GEMM 3x3 conv (stages 2-4) ----------------
// Round-10 config (session best), stats stripped from epilogue (now in
// bnstats_g): 128 co x 256 px (2 output rows) per block, wave 64co x 128px,
// acc[4][8]. Per (cb,dy) event: A 24KB (3 dx taps) [+ B 36KB (4 rows) at
// dy==0]; 96 MFMA/wave/event. Static LDS 60KB, (256,2) -> 2 blocks/CU.
__global__ __launch_bounds__(256, 2) void convmfma_k(
    const bf16_t* __restrict__ xmT, const bf16_t* __restrict__ wt2,
    const float* __restrict__ bias, const float* __restrict__ scale,
    const float* __restrict__ mnext, bf16_t* __restrict__ y, int H, int NCB, int Co,
    int Co_pad) {
  __shared__ bf16_t Ab[3][4096];  // 24KB: 3 dx taps x [g][co128][8]
  __shared__ bf16_t Bb[4][4608];  // 36KB: 4 input rows x 9 chunks
  const int tid = threadIdx.x;
  const int lane = tid & 63;
  const int wave = tid >> 6;
  const int wm = wave >> 1;  // co half
  const int wn = wave & 1;   // output row within pair
  const int g = lane >> 4;   // k-group of 8
  const int ln = lane & 15;  // frag row/col
  const int coTile = blockIdx.x * 128;
  const int Hh = H >> 1;
  const int bx = blockIdx.y;  // n*Hh + ypair
  const int n = bx / Hh, y0 = (bx % Hh) * 2;

  f32x4 acc[4][8];
#pragma unroll
  for (int mf = 0; mf < 4; mf++)
#pragma unroll
    for (int nf = 0; nf < 8; nf++) acc[mf][nf] = (f32x4)(0.f);

  const size_t cbStride = 4608;  // elems per (row, cb) slice
  const size_t rowStrideG = (size_t)NCB * cbStride;
  // padded row index y0 corresponds to input row y0-1
  const size_t gRow0 = ((size_t)n * (H + 2) + y0) * rowStrideG;
  const size_t laneOff = (size_t)lane * 8;  // identity: lane L -> L*16B

  for (int cb = 0; cb < NCB; ++cb) {
#pragma unroll
    for (int dy = 0; dy < 3; ++dy) {
      __syncthreads();  // previous event's LDS reads done
      if (dy == 0) {
        // stage B: 4 input rows (y0-1 .. y0+2) of this cb, 36 chunks
        const bf16_t* bsrc = xmT + gRow0 + (size_t)cb * cbStride;
        for (int c = wave; c < 36; c += 4) {
          int row = c / 9, chk = c - row * 9;
          __builtin_amdgcn_global_load_lds(
              (const __attribute__((address_space(1))) void*)(
                  bsrc + (size_t)row * rowStrideG + chk * 512 + laneOff),
              (__attribute__((address_space(3))) void*)(&Bb[row][chk * 512]), 16, 0, 0);
        }
      }
      // stage A: taps dy*3+{0,1,2}, 24 chunks
      for (int c = wave; c < 24; c += 4) {
        int tl = c >> 3, cc = c & 7;
        int tap = dy * 3 + tl;
        const bf16_t* asrc =
            wt2 + ((((size_t)tap * NCB + cb) * 4 + (cc >> 1)) * Co_pad + coTile +
                   (cc & 1) * 64) * 8;
        __builtin_amdgcn_global_load_lds(
            (const __attribute__((address_space(1))) void*)(asrc + laneOff),
            (__attribute__((address_space(3))) void*)(&Ab[tl][cc * 512]), 16, 0, 0);
      }
      __syncthreads();  // staging visible

      const bf16_t* brow = &Bb[wn + dy][0];
#pragma unroll
      for (int dx = 0; dx < 3; ++dx) {
        bf16x8 a[4];
#pragma unroll
        for (int mf = 0; mf < 4; ++mf)
          a[mf] = *(const bf16x8*)(Ab[dx] + (g * 128 + wm * 64 + mf * 16 + ln) * 8);
#pragma unroll
        for (int nf = 0; nf < 8; ++nf) {
          int colx = nf * 16 + ln + dx;
          bf16x8 b =
              *(const bf16x8*)(brow + ((colx >> 4) * 4 + g) * 128 + (colx & 15) * 8);
#pragma unroll
          for (int mf = 0; mf < 4; ++mf)
            acc[mf][nf] =
                __builtin_amdgcn_mfma_f32_16x16x32_bf16(a[mf], b, acc[mf][nf], 0, 0, 0);
        }
      }
    }
  }

  // epilogue: partial-conv scale + bias + mask, write NHWC bf16
  const int yrow = y0 + wn;
  const int pixBase = (n * H + yrow) * WD;
  float scl[8], msk[8];
#pragma unroll
  for (int nf = 0; nf < 8; ++nf) {
    int x = nf * 16 + ln;
    scl[nf] = scale[pixBase + x];
    msk[nf] = mnext[pixBase + x];
  }
#pragma unroll
  for (int mf = 0; mf < 4; ++mf) {
    if (coTile + wm * 64 + mf * 16 >= Co) continue;  // padded frag
    int coB = coTile + wm * 64 + mf * 16 + g * 4;
    f32x4 bias4 = *(const f32x4*)&bias[coB];
#pragma unroll
    for (int nf = 0; nf < 8; ++nf) {
      int x = nf * 16 + ln;
      bf16x4 o;
#pragma unroll
      for (int r = 0; r < 4; ++r)
        o[r] = (bf16_t)((acc[mf][nf][r] * scl[nf] + bias4[r]) * msk[nf]);
      *(bf16x4*)&y[(size_t)(pixBase + x) * Co + coB] = o;
    }
  }
}

// ---------------- BN finalize ----------------
__global__ void bnfin_k(const float* __restrict__ sums, const float* __restrict__ g,
                        const float* __restrict__ be, float* __restrict__ ab, int Co,
                        float invCount) {
  int c = blockIdx.x * 64 + threadIdx.x;
  if (c >= Co) return;
  float mean = sums[c] * invCount;
  float var = sums[Co + c] * invCount - mean * mean;
  float rs = rsqrtf(var + 1e-5f);
  float a = g[c] * rs;
  ab[c] = a;
  ab[Co + c] = be[c] - mean * a;
}

// ---------------- BN + ReLU + (2,1) pool + mask -> chunked padded xmT ----------------
// out layout: [n][Hp+2][NCBn][9 chunks][g][col16][8]
__global__ void bnpool_k(const bf16_t* __restrict__ y, const float* __restrict__ ab,
                         const float* __restrict__ mp, bf16_t* __restrict__ out, int C,
                         int NCBn, int H) {
  int Hp = H / 2;
  int Cq = C / 8;
  int tid = blockIdx.x * 256 + threadIdx.x;
  int total = NB * Hp * WD * Cq;
  if (tid >= total) return;
  int c8 = tid % Cq;
  int t = tid / Cq;
  int x = t % WD;
  t /= WD;
  int yo = t % Hp;
  int n = t / Hp;
  int c = c8 * 8;
  const bf16_t* p0 = y + ((size_t)((n * H + 2 * yo) * WD + x)) * C + c;
  const bf16_t* p1 = p0 + (size_t)WD * C;
  float mpv = mp[(n * Hp + yo) * WD + x];
  bf16x8 v0 = *(const bf16x8*)p0;
  bf16x8 v1 = *(const bf16x8*)p1;
  bf16x8 o;
#pragma unroll
  for (int j = 0; j < 8; ++j) {
    float a = ab[c + j], sh = ab[C + c + j];
    float f0 = (float)v0[j] * a + sh;
    float f1 = (float)v1[j] * a + sh;
    o[j] = (bf16_t)(fmaxf(fmaxf(f0, f1), 0.f) * mpv);
  }
  int cb = c >> 5;           // 32-ci block
  int gg = (c & 31) >> 3;    // k-group within block
  int col = x + 1;           // stored col (1..128)
  int chk = col >> 4, lcol = col & 15;
  *(bf16x8*)&out[((((size_t)n * (Hp + 2) + yo + 1) * NCBn + cb) * 9 + chk) * 512 +
                 gg * 128 + lcol * 8] = o;
}

// ---------------- stage-4: BN + ReLU + pool + global mean -> feat ----------------
__global__ void bnfeat_k(const bf16_t* __restrict__ y, const float* __restrict__ ab,
                         float* __restrict__ feat) {
  int n = blockIdx.x, cc = blockIdx.y, yo = blockIdx.z;
  int c = cc * 128 + threadIdx.x;  // C = 640
  float a = ab[c], sh = ab[640 + c];
  float s = 0.f;
  for (int x = 0; x < WD; ++x) {
    size_t p0 = ((size_t)(n * 32 + 2 * yo) * WD + x) * 640 + c;
    float v0 = (float)y[p0] * a + sh;
    float v1 = (float)y[p0 + (size_t)WD * 640] * a + sh;
    s += fmaxf(fmaxf(v0, v1), 0.f);
  }
  atomicAdd(&feat[n * 640 + c], s * (1.f / 2048.f));
}

// ---------------- fc1 (640->256) + relu ----------------
__global__ void fc1_k(const float* __restrict__ feat, const float* __restrict__ fw,
                      const float* __restrict__ fb, float* __restrict__ z1) {
  int n = blockIdx.x;
  int o = threadIdx.x;
  const float* f = feat + n * 640;
  const float* wr = fw + o * 640;
  float s = fb[o];
  for (int k = 0; k < 640; k++) s += f[k] * wr[k];
  z1[n * 256 + o] = fmaxf(s, 0.f);
}

// ---------------- fc2 (256->128) + relu + head + sigmoid ----------------
__global__ void fc2h_k(const float* __restrict__ z1, const float* __restrict__ fw2,
                       const float* __restrict__ fb2, const float* __restrict__ hw,
                       const float* __restrict__ hb, float* __restrict__ out) {
  int n = blockIdx.x;
  int o = threadIdx.x;
  const float* zr = z1 + n * 256;
  const float* wr = fw2 + o * 256;
  float s = fb2[o];
  for (int k = 0; k < 256; k++) s += zr[k] * wr[k];
  s = fmaxf(s, 0.f) * hw[o];
#pragma unroll
  for (int off = 32; off >= 1; off >>= 1) s += __shfl_down(s, off, 64);
  __shared__ float red[2];
  if ((threadIdx.x & 63) == 0) red[threadIdx.x >> 6] = s;
  __syncthreads();
  if (threadIdx.x == 0) {
    float t = red[0] + red[1] + hb[0];
    out[n] = 1.f / (1.f + expf(-t));
  }
}

extern "C" void kernel_launch(void* const* d_in, const int* in_sizes, int n_in,
                              void* d_out, int out_size, void* d_ws, size_t ws_size,
                              hipStream_t stream) {
  const float* x = (const float*)d_in[0];
  const float* wgt[4] = {(const float*)d_in[1], (const float*)d_in[5],
                         (const float*)d_in[9], (const float*)d_in[13]};
  const float* bias[4] = {(const float*)d_in[2], (const float*)d_in[6],
                          (const float*)d_in[10], (const float*)d_in[14]};
  const float* gam[4] = {(const float*)d_in[3], (const float*)d_in[7],
                         (const float*)d_in[11], (const float*)d_in[15]};
  const float* bet[4] = {(const float*)d_in[4], (const float*)d_in[8],
                         (const float*)d_in[12], (const float*)d_in[16]};
  const float* fw1 = (const float*)d_in[17];
  const float* fb1 = (const float*)d_in[18];
  const float* fw2 = (const float*)d_in[19];
  const float* fb2 = (const float*)d_in[20];
  const float* hw = (const float*)d_in[21];
  const float* hb = (const float*)d_in[22];

  char* base = (char*)d_ws;
  size_t off = 0;
  auto alloc = [&](size_t bytes) {
    char* p = base + off;
    off += (bytes + 255) & ~(size_t)255;
    return p;
  };
  bf16_t* bufY = (bf16_t*)alloc(83886080);  // 41,943,040 bf16
  const size_t xmtElems = 28786688;         // 16*130*3*4608 + 32768 slack
  bf16_t* xmT0 = (bf16_t*)alloc(xmtElems * 2);
  bf16_t* xmT1 = (bf16_t*)alloc(xmtElems * 2);
  bf16_t* wt2 = (bf16_t*)alloc(3686400);
  float* data = (float*)alloc(2097152);
  float* mask0 = (float*)alloc(2097152);
  float* mask1 = (float*)alloc(2097152);
  float* scaleB = (float*)alloc(2097152);
  float* mnextB = (float*)alloc(2097152);
  float* sums = (float*)alloc(5120);
  float* bnab = (float*)alloc(5120);
  float* feat = (float*)alloc(40960);
  float* z1 = (float*)alloc(16384);

  zero_k<<<40, 256, 0, stream>>>(feat, 10240);

  // split input
  split_k<<<(NB * 256 * 128 + 255) / 256, 256, 0, stream>>>(x, data, mask0);

  // ---------- stage 1 (direct, Ci=1, Co=80, H=256) ----------
  {
    int H = 256;
    int tot = NB * H * WD;
    maskscale_k<<<(tot + 255) / 256, 256, 0, stream>>>(mask0, scaleB, mnextB, H, 1.0f);
    zero_k<<<1, 256, 0, stream>>>(sums, 160);
    pconv1_k<<<tot / 256, 256, 0, stream>>>(data, mask0, wgt[0], bias[0], scaleB,
                                            mnextB, bufY);
    bnstats_g<<<256, 320, 0, stream>>>(bufY, sums, 10);
    bnfin_k<<<2, 64, 0, stream>>>(sums, gam[0], bet[0], bnab, 80,
                                  1.0f / (NB * (float)H * WD));
    maskpool_k<<<(NB * (H / 2) * WD + 255) / 256, 256, 0, stream>>>(mnextB, mask1, H);
    // border-zero xmT0 for (Hp=128, NCB=3) then pool into it
    {
      int tr = NB * 2 * 3 * 576, tc = NB * 128 * 3 * 8;
      zrows_k<<<(tr + 255) / 256, 256, 0, stream>>>(xmT0, 128, 3);
      zcols_k<<<(tc + 255) / 256, 256, 0, stream>>>(xmT0, 128, 3);
    }
    int totp = NB * (H / 2) * WD * (80 / 8);
    bnpool_k<<<(totp + 255) / 256, 256, 0, stream>>>(bufY, bnab, mask1, xmT0, 80, 3, H);
  }

  // ---------- stages 2-4 (MFMA implicit GEMM) ----------
  const int CiS[3] = {80, 160, 320};
  const int NCBS[3] = {3, 5, 10};
  const int CoS[3] = {160, 320, 640};
  const int CopS[3] = {256, 384, 640};
  const int HS[3] = {128, 64, 32};
  bf16_t* xin[3] = {xmT0, xmT1, xmT0};
  bf16_t* xout[3] = {xmT1, xmT0, nullptr};
  float* mIn[3] = {mask1, mask0, mask1};
  float* mOut[3] = {mask0, mask1, nullptr};

  for (int s = 0; s < 3; ++s) {
    int H = HS[s], Ci = CiS[s], NCB = NCBS[s], Co = CoS[s], Cop = CopS[s];
    int wtot = 9 * NCB * Cop * 32;
    wtrans_k<<<(wtot + 255) / 256, 256, 0, stream>>>(wgt[s + 1], wt2, Ci, Co, NCB, Cop);
    int tot = NB * H * WD;
    maskscale_k<<<(tot + 255) / 256, 256, 0, stream>>>(mIn[s], scaleB, mnextB, H,
                                                       (float)Ci);
    convmfma_k<<<dim3(Cop / 128, NB * (H / 2)), 256, 0, stream>>>(
        xin[s], wt2, bias[s + 1], scaleB, mnextB, bufY, H, NCB, Co, Cop);
    zero_k<<<(2 * Co + 255) / 256, 256, 0, stream>>>(sums, 2 * Co);
    bnstats_g<<<256, 320, 0, stream>>>(bufY, sums, Co / 8);
    bnfin_k<<<(Co + 63) / 64, 64, 0, stream>>>(sums, gam[s + 1], bet[s + 1], bnab, Co,
                                               1.0f / (NB * (float)H * WD));
    if (s < 2) {
      maskpool_k<<<(NB * (H / 2) * WD + 255) / 256, 256, 0, stream>>>(mnextB, mOut[s], H);
      int Hpn = H / 2, NCBn = NCBS[s + 1];
      int tr = NB * 2 * NCBn * 576, tc = NB * Hpn * NCBn * 8;
      zrows_k<<<(tr + 255) / 256, 256, 0, stream>>>(xout[s], Hpn, NCBn);
      zcols_k<<<(tc + 255) / 256, 256, 0, stream>>>(xout[s], Hpn, NCBn);
      int totp = NB * (H / 2) * WD * (Co / 8);
      bnpool_k<<<(totp + 255) / 256, 256, 0, stream>>>(bufY, bnab, mOut[s], xout[s], Co,
                                                       NCBn, H);
    } else {
      bnfeat_k<<<dim3(16, 5, 16), 128, 0, stream>>>(bufY, bnab, feat);
    }
  }

  fc1_k<<<16, 256, 0, stream>>>(feat, fw1, fb1, z1);
  fc2h_k<<<16, 128, 0, stream>>>(z1, fw2, fb2, hw, hb, (float*)d_out);
}

// Round 15
// 822.883 us; speedup vs baseline: 6.2956x; 1.0247x over previous
//
#include <hip/hip_runtime.h>
#include <math.h>

#define NB 16
#define WD 128

typedef __bf16 bf16_t;
typedef __bf16 bf16x8 __attribute__((ext_vector_type(8)));
typedef __bf16 bf16x4 __attribute__((ext_vector_type(4)));
typedef float f32x4 __attribute__((ext_vector_type(4)));

// ---------------- zero helper ----------------
__global__ void zero_k(float* __restrict__ p, int n) {
  int i = blockIdx.x * 256 + threadIdx.x;
  if (i < n) p[i] = 0.f;
}

// ---------------- combined border zeroing for xmT buffers ----------------
// layout: [n][Hp+2][NCB][9 chunks][512]. Zeros: padded rows 0 and Hp+1, plus
// interior-row pad cols (stored col 0 -> chunk0 [g][0][8]; col 129 -> chunk8
// [g][1][8]). ~7MB instead of a 115MB full memset.
__global__ void zb_k(bf16_t* __restrict__ out, int Hp, int NCB) {
  int trow = NB * 2 * NCB * 576;
  int tcol = NB * Hp * NCB * 8;
  int i = blockIdx.x * 256 + threadIdx.x;
  bf16x8 z = (bf16x8)(bf16_t)0.f;
  if (i < trow) {
    int e = i % 576;
    int t = i / 576;
    int cb = t % NCB;
    t /= NCB;
    int rsel = t & 1;
    int n = t >> 1;
    int row = rsel ? (Hp + 1) : 0;
    *(bf16x8*)&out[(((size_t)n * (Hp + 2) + row) * NCB + cb) * 4608 + e * 8] = z;
  } else if (i < trow + tcol) {
    int k = i - trow;
    int j = k & 7;
    int t = k >> 3;
    int cb = t % NCB;
    t /= NCB;
    int row = (t % Hp) + 1;
    int n = t / Hp;
    size_t base = (((size_t)n * (Hp + 2) + row) * NCB + cb) * 4608;
    size_t off = (j < 4) ? (size_t)(j * 128) : (size_t)(4096 + (j - 4) * 128 + 8);
    *(bf16x8*)&out[base + off] = z;
  }
}

// ---------------- split input into data / clipped mask ----------------
__global__ void split_k(const float* __restrict__ x, float* __restrict__ data,
                        float* __restrict__ mask) {
  const int HW = 256 * 128;
  int i = blockIdx.x * 256 + threadIdx.x;
  if (i >= NB * HW) return;
  int n = i / HW, rem = i % HW;
  data[i] = x[(size_t)(n * 2) * HW + rem];
  float mv = x[(size_t)(n * 2 + 1) * HW + rem];
  mask[i] = fminf(fmaxf(mv, 0.f), 1.f);
}

// ---------------- fused mask 3x3 sum -> scale/mnext (2 rows) + (2,1) pool ----------------
__global__ void maskscale2_k(const float* __restrict__ m, float* __restrict__ scale,
                             float* __restrict__ mnext, float* __restrict__ mpool,
                             int H, float Ci) {
  int Hp = H / 2;
  int i = blockIdx.x * 256 + threadIdx.x;
  int tot = NB * Hp * WD;
  if (i >= tot) return;
  int x = i % WD;
  int t = i / WD;
  int yo = t % Hp;
  int n = t / Hp;
  const float* mn_ = m + (size_t)n * H * WD;
  float mx[2];
#pragma unroll
  for (int r = 0; r < 2; ++r) {
    int y = 2 * yo + r;
    float s = 0.f;
#pragma unroll
    for (int dy = -1; dy <= 1; dy++) {
      int yy = y + dy;
#pragma unroll
      for (int dx = -1; dx <= 1; dx++) {
        int xx = x + dx;
        float v = 1.0f;
        if (yy >= 0 && yy < H && xx >= 0 && xx < WD) v = mn_[yy * WD + xx];
        s += v;
      }
    }
    float valid = Ci * s;
    int p = (n * H + y) * WD + x;
    scale[p] = (9.0f * Ci) / fmaxf(valid, 1.0f);
    float mnx = (valid <= 0.0f) ? 0.f : 1.f;
    mnext[p] = mnx;
    mx[r] = mnx;
  }
  mpool[((size_t)n * Hp + yo) * WD + x] = fmaxf(mx[0], mx[1]);
}

// ---------------- stage-1 direct conv (Ci=1), NHWC bf16 out ----------------
__global__ void pconv1_k(const float* __restrict__ data, const float* __restrict__ mask,
                         const float* __restrict__ w, const float* __restrict__ b,
                         const float* __restrict__ scale, const float* __restrict__ mnext,
                         bf16_t* __restrict__ y) {
  __shared__ float ws[720];
  __shared__ float bs[80];
  for (int i = threadIdx.x; i < 720; i += 256) ws[i] = w[i];
  if (threadIdx.x < 80) bs[threadIdx.x] = b[threadIdx.x];
  __syncthreads();
  const int H = 256;
  int p = blockIdx.x * 256 + threadIdx.x;
  int x = p % WD;
  int t = p / WD;
  int yy = t % H;
  int n = t / H;
  const float* dn = data + (size_t)n * H * WD;
  const float* mn = mask + (size_t)n * H * WD;
  float v[9];
#pragma unroll
  for (int dy = 0; dy < 3; dy++) {
    int yv = yy - 1 + dy;
#pragma unroll
    for (int dx = 0; dx < 3; dx++) {
      int xv = x - 1 + dx;
      float u = 0.f;
      if (yv >= 0 && yv < H && xv >= 0 && xv < WD)
        u = dn[yv * WD + xv] * mn[yv * WD + xv];
      v[dy * 3 + dx] = u;
    }
  }
  float sc = scale[p], mx = mnext[p];
  bf16_t* yp = y + (size_t)p * 80;
#pragma unroll
  for (int c8 = 0; c8 < 10; ++c8) {
    bf16x8 o;
#pragma unroll
    for (int j = 0; j < 8; ++j) {
      int co = c8 * 8 + j;
      float s = 0.f;
#pragma unroll
      for (int tt = 0; tt < 9; ++tt) s += ws[co * 9 + tt] * v[tt];
      o[j] = (bf16_t)((s * sc + bs[co]) * mx);
    }
    *(bf16x8*)(yp + c8 * 8) = o;
  }
}

// ---------------- generic BN stats over NHWC bf16 (C = nc8*8, nc8 | 320) ----------------
__global__ __launch_bounds__(320) void bnstats_g(const bf16_t* __restrict__ y,
                                                 float* __restrict__ sums, int nc8) {
  const int ITER = 64;
  const int tid = threadIdx.x;
  const int C = nc8 * 8;
  float s[8], q[8];
#pragma unroll
  for (int j = 0; j < 8; ++j) { s[j] = 0.f; q[j] = 0.f; }
  size_t base = (size_t)blockIdx.x * 320 * ITER;
  for (int k = 0; k < ITER; ++k) {
    size_t chunk = base + (size_t)k * 320 + tid;
    bf16x8 v = *(const bf16x8*)(y + chunk * 8);
#pragma unroll
    for (int j = 0; j < 8; ++j) {
      float f = (float)v[j];
      s[j] += f;
      q[j] += f * f;
    }
  }
  __shared__ float red[320][8];
  const int rows = 320 / nc8;
  float ssum[2], qsum[2];
#pragma unroll
  for (int j = 0; j < 8; ++j) red[tid][j] = s[j];
  __syncthreads();
  {
    int idx = 0;
    for (int c = tid; c < C; c += 320, ++idx) {
      int c8 = c >> 3, j = c & 7;
      float acc = 0.f;
      for (int i = 0; i < rows; ++i) acc += red[c8 + nc8 * i][j];
      ssum[idx] = acc;
    }
  }
  __syncthreads();
#pragma unroll
  for (int j = 0; j < 8; ++j) red[tid][j] = q[j];
  __syncthreads();
  {
    int idx = 0;
    for (int c = tid; c < C; c += 320, ++idx) {
      int c8 = c >> 3, j = c & 7;
      float acc = 0.f;
      for (int i = 0; i < rows; ++i) acc += red[c8 + nc8 * i][j];
      qsum[idx] = acc;
      atomicAdd(&sums[c], ssum[idx]);
      atomicAdd(&sums[C + c], qsum[idx]);
    }
  }
}

// ---------------- weight transform: w[co][ci][3][3] fp32 -> wt2 bf16 ----------------
// wt2 index: (((tap*NCB + cb)*4 + g)*Co_pad + co)*8 + j   (ci = cb*32 + g*8 + j)
__global__ void wtrans_k(const float* __restrict__ w, bf16_t* __restrict__ wt2,
                         int Ci, int Co, int NCB, int Co_pad) {
  int idx = blockIdx.x * 256 + threadIdx.x;
  int total = 9 * NCB * Co_pad * 32;
  if (idx >= total) return;
  int j = idx & 7;
  int rest = idx >> 3;
  int co = rest % Co_pad;
  int rest2 = rest / Co_pad;
  int g = rest2 & 3;
  int rest3 = rest2 >> 2;
  int cb = rest3 % NCB;
  int tap = rest3 / NCB;
  int ci = cb * 32 + g * 8 + j;
  float v = 0.f;
  if (co < Co && ci < Ci) v = w[((size_t)co * Ci + ci) * 9 + tap];
  wt2[idx] = (bf16_t)v;
}

// ---------------- MFMA implicit-GEMM 3x3 conv (stages 2-4) ----------------
// r10/r14 core (best: 45% MfmaUtil): 128 co x 256 px (2 output rows)/block,
// wave 64co x 128px, acc[4][8], A 24KB / B 36KB staging, 96 MFMA/wave/event,
// 2 blocks/CU. NEW: epilogue transposes through LDS (Bb reuse, pix-stride
// 136 for 16B alignment) so global stores are contiguous 256B/pixel runs --
// r14 showed 143MB WRITE vs 84MB output (8B scatter, 1 line per lane).
__global__ __launch_bounds__(256, 2) void convmfma_k(
    const bf16_t* __restrict__ xmT, const bf16_t* __restrict__ wt2,
    const float* __restrict__ bias, const float* __restrict__ scale,
    const float* __restrict__ mnext, bf16_t* __restrict__ y, int H, int NCB, int Co,
    int Co_pad) {
  __shared__ bf16_t Ab[3][4096];  // 24KB: 3 dx taps x [g][co128][8]
  __shared__ bf16_t Bb[4][4608];  // 36KB: 4 input rows x 9 chunks; epilogue scratch
  const int tid = threadIdx.x;
  const int lane = tid & 63;
  const int wave = tid >> 6;
  const int wm = wave >> 1;  // co half
  const int wn = wave & 1;   // output row within pair
  const int g = lane >> 4;   // k-group of 8
  const int ln = lane & 15;  // frag row/col
  const int coTile = blockIdx.x * 128;
  const int Hh = H >> 1;
  const int bx = blockIdx.y;  // n*Hh + ypair
  const int n = bx / Hh, y0 = (bx % Hh) * 2;

  f32x4 acc[4][8];
#pragma unroll
  for (int mf = 0; mf < 4; mf++)
#pragma unroll
    for (int nf = 0; nf < 8; nf++) acc[mf][nf] = (f32x4)(0.f);

  const size_t cbStride = 4608;  // elems per (row, cb) slice
  const size_t rowStrideG = (size_t)NCB * cbStride;
  const size_t gRow0 = ((size_t)n * (H + 2) + y0) * rowStrideG;
  const size_t laneOff = (size_t)lane * 8;  // identity: lane L -> L*16B

  for (int cb = 0; cb < NCB; ++cb) {
#pragma unroll
    for (int dy = 0; dy < 3; ++dy) {
      __syncthreads();  // previous event's LDS reads done
      if (dy == 0) {
        // stage B: 4 input rows (y0-1 .. y0+2) of this cb, 36 chunks
        const bf16_t* bsrc = xmT + gRow0 + (size_t)cb * cbStride;
        for (int c = wave; c < 36; c += 4) {
          int row = c / 9, chk = c - row * 9;
          __builtin_amdgcn_global_load_lds(
              (const __attribute__((address_space(1))) void*)(
                  bsrc + (size_t)row * rowStrideG + chk * 512 + laneOff),
              (__attribute__((address_space(3))) void*)(&Bb[row][chk * 512]), 16, 0, 0);
        }
      }
      // stage A: taps dy*3+{0,1,2}, 24 chunks
      for (int c = wave; c < 24; c += 4) {
        int tl = c >> 3, cc = c & 7;
        int tap = dy * 3 + tl;
        const bf16_t* asrc =
            wt2 + ((((size_t)tap * NCB + cb) * 4 + (cc >> 1)) * Co_pad + coTile +
                   (cc & 1) * 64) * 8;
        __builtin_amdgcn_global_load_lds(
            (const __attribute__((address_space(1))) void*)(asrc + laneOff),
            (__attribute__((address_space(3))) void*)(&Ab[tl][cc * 512]), 16, 0, 0);
      }
      __syncthreads();  // staging visible

      const bf16_t* brow = &Bb[wn + dy][0];
#pragma unroll
      for (int dx = 0; dx < 3; ++dx) {
        bf16x8 a[4];
#pragma unroll
        for (int mf = 0; mf < 4; ++mf)
          a[mf] = *(const bf16x8*)(Ab[dx] + (g * 128 + wm * 64 + mf * 16 + ln) * 8);
#pragma unroll
        for (int nf = 0; nf < 8; ++nf) {
          int colx = nf * 16 + ln + dx;
          bf16x8 b =
              *(const bf16x8*)(brow + ((colx >> 4) * 4 + g) * 128 + (colx & 15) * 8);
#pragma unroll
          for (int mf = 0; mf < 4; ++mf)
            acc[mf][nf] =
                __builtin_amdgcn_mfma_f32_16x16x32_bf16(a[mf], b, acc[mf][nf], 0, 0, 0);
        }
      }
    }
  }

  // ---- epilogue: scale+bias+mask, LDS transpose, coalesced bf16x8 stores ----
  const int yrowW = y0 + wn;
  const int pixBaseW = (n * H + yrowW) * WD;
  float scl[8], msk[8];
#pragma unroll
  for (int nf = 0; nf < 8; ++nf) {
    int x = nf * 16 + ln;
    scl[nf] = scale[pixBaseW + x];
    msk[nf] = mnext[pixBaseW + x];
  }
  bf16_t* ep = &Bb[0][0];  // 128px x (co stride 136) x 2B = 34816B <= 36864B
#pragma unroll
  for (int rp = 0; rp < 2; ++rp) {
    __syncthreads();  // main-loop reads / previous pass stores done
    if (wn == rp) {
#pragma unroll
      for (int mf = 0; mf < 4; ++mf) {
        int cbase = wm * 64 + mf * 16;
        if (coTile + cbase < Co) {  // Co % 16 == 0; guard bias read
          f32x4 bias4 = *(const f32x4*)&bias[coTile + cbase + g * 4];
#pragma unroll
          for (int nf = 0; nf < 8; ++nf) {
            bf16x4 o;
#pragma unroll
            for (int r = 0; r < 4; ++r)
              o[r] = (bf16_t)((acc[mf][nf][r] * scl[nf] + bias4[r]) * msk[nf]);
            *(bf16x4*)&ep[(nf * 16 + ln) * 136 + cbase + g * 4] = o;
          }
        }
      }
    }
    __syncthreads();
    const int prow = (n * H + y0 + rp) * WD;
    const int c8 = tid & 15;
    const int coG = coTile + c8 * 8;
    if (coG < Co) {
      const int psub = tid >> 4;
#pragma unroll
      for (int it = 0; it < 8; ++it) {
        int p = it * 16 + psub;
        bf16x8 v = *(const bf16x8*)&ep[p * 136 + c8 * 8];
        *(bf16x8*)&y[(size_t)(prow + p) * Co + coG] = v;
      }
    }
  }
}

// ---------------- BN finalize ----------------
__global__ void bnfin_k(const float* __restrict__ sums, const float* __restrict__ g,
                        const float* __restrict__ be, float* __restrict__ ab, int Co,
                        float invCount) {
  int c = blockIdx.x * 64 + threadIdx.x;
  if (c >= Co) return;
  float mean = sums[c] * invCount;
  float var = sums[Co + c] * invCount - mean * mean;
  float rs = rsqrtf(var + 1e-5f);
  float a = g[c] * rs;
  ab[c] = a;
  ab[Co + c] = be[c] - mean * a;
}

// ---------------- BN + ReLU + (2,1) pool + mask -> chunked padded xmT ----------------
// out layout: [n][Hp+2][NCBn][9 chunks][g][col16][8]
__global__ void bnpool_k(const bf16_t* __restrict__ y, const float* __restrict__ ab,
                         const float* __restrict__ mp, bf16_t* __restrict__ out, int C,
                         int NCBn, int H) {
  int Hp = H / 2;
  int Cq = C / 8;
  int tid = blockIdx.x * 256 + threadIdx.x;
  int total = NB * Hp * WD * Cq;
  if (tid >= total) return;
  int c8 = tid % Cq;
  int t = tid / Cq;
  int x = t % WD;
  t /= WD;
  int yo = t % Hp;
  int n = t / Hp;
  int c = c8 * 8;
  const bf16_t* p0 = y + ((size_t)((n * H + 2 * yo) * WD + x)) * C + c;
  const bf16_t* p1 = p0 + (size_t)WD * C;
  float mpv = mp[(n * Hp + yo) * WD + x];
  bf16x8 v0 = *(const bf16x8*)p0;
  bf16x8 v1 = *(const bf16x8*)p1;
  bf16x8 o;
#pragma unroll
  for (int j = 0; j < 8; ++j) {
    float a = ab[c + j], sh = ab[C + c + j];
    float f0 = (float)v0[j] * a + sh;
    float f1 = (float)v1[j] * a + sh;
    o[j] = (bf16_t)(fmaxf(fmaxf(f0, f1), 0.f) * mpv);
  }
  int cb = c >> 5;           // 32-ci block
  int gg = (c & 31) >> 3;    // k-group within block
  int col = x + 1;           // stored col (1..128)
  int chk = col >> 4, lcol = col & 15;
  *(bf16x8*)&out[((((size_t)n * (Hp + 2) + yo + 1) * NCBn + cb) * 9 + chk) * 512 +
                 gg * 128 + lcol * 8] = o;
}

// ---------------- stage-4: BN + ReLU + pool + global mean -> feat ----------------
__global__ void bnfeat_k(const bf16_t* __restrict__ y, const float* __restrict__ ab,
                         float* __restrict__ feat) {
  int n = blockIdx.x, cc = blockIdx.y, yo = blockIdx.z;
  int c = cc * 128 + threadIdx.x;  // C = 640
  float a = ab[c], sh = ab[640 + c];
  float s = 0.f;
  for (int x = 0; x < WD; ++x) {
    size_t p0 = ((size_t)(n * 32 + 2 * yo) * WD + x) * 640 + c;
    float v0 = (float)y[p0] * a + sh;
    float v1 = (float)y[p0 + (size_t)WD * 640] * a + sh;
    s += fmaxf(fmaxf(v0, v1), 0.f);
  }
  atomicAdd(&feat[n * 640 + c], s * (1.f / 2048.f));
}

// ---------------- fc1 (640->256) + relu ----------------
__global__ void fc1_k(const float* __restrict__ feat, const float* __restrict__ fw,
                      const float* __restrict__ fb, float* __restrict__ z1) {
  int n = blockIdx.x;
  int o = threadIdx.x;
  const float* f = feat + n * 640;
  const float* wr = fw + o * 640;
  float s = fb[o];
  for (int k = 0; k < 640; k++) s += f[k] * wr[k];
  z1[n * 256 + o] = fmaxf(s, 0.f);
}

// ---------------- fc2 (256->128) + relu + head + sigmoid ----------------
__global__ void fc2h_k(const float* __restrict__ z1, const float* __restrict__ fw2,
                       const float* __restrict__ fb2, const float* __restrict__ hw,
                       const float* __restrict__ hb, float* __restrict__ out) {
  int n = blockIdx.x;
  int o = threadIdx.x;
  const float* zr = z1 + n * 256;
  const float* wr = fw2 + o * 256;
  float s = fb2[o];
  for (int k = 0; k < 256; k++) s += zr[k] * wr[k];
  s = fmaxf(s, 0.f) * hw[o];
#pragma unroll
  for (int off = 32; off >= 1; off >>= 1) s += __shfl_down(s, off, 64);
  __shared__ float red[2];
  if ((threadIdx.x & 63) == 0) red[threadIdx.x >> 6] = s;
  __syncthreads();
  if (threadIdx.x == 0) {
    float t = red[0] + red[1] + hb[0];
    out[n] = 1.f / (1.f + expf(-t));
  }
}

extern "C" void kernel_launch(void* const* d_in, const int* in_sizes, int n_in,
                              void* d_out, int out_size, void* d_ws, size_t ws_size,
                              hipStream_t stream) {
  const float* x = (const float*)d_in[0];
  const float* wgt[4] = {(const float*)d_in[1], (const float*)d_in[5],
                         (const float*)d_in[9], (const float*)d_in[13]};
  const float* bias[4] = {(const float*)d_in[2], (const float*)d_in[6],
                          (const float*)d_in[10], (const float*)d_in[14]};
  const float* gam[4] = {(const float*)d_in[3], (const float*)d_in[7],
                         (const float*)d_in[11], (const float*)d_in[15]};
  const float* bet[4] = {(const float*)d_in[4], (const float*)d_in[8],
                         (const float*)d_in[12], (const float*)d_in[16]};
  const float* fw1 = (const float*)d_in[17];
  const float* fb1 = (const float*)d_in[18];
  const float* fw2 = (const float*)d_in[19];
  const float* fb2 = (const float*)d_in[20];
  const float* hw = (const float*)d_in[21];
  const float* hb = (const float*)d_in[22];

  char* base = (char*)d_ws;
  size_t off = 0;
  auto alloc = [&](size_t bytes) {
    char* p = base + off;
    off += (bytes + 255) & ~(size_t)255;
    return p;
  };
  bf16_t* bufY = (bf16_t*)alloc(83886080);  // 41,943,040 bf16
  const size_t xmtElems = 28786688;         // 16*130*3*4608 + 32768 slack
  bf16_t* xmT0 = (bf16_t*)alloc(xmtElems * 2);
  bf16_t* xmT1 = (bf16_t*)alloc(xmtElems * 2);
  bf16_t* wt2 = (bf16_t*)alloc(3686400);
  float* data = (float*)alloc(2097152);
  float* mask0 = (float*)alloc(2097152);
  float* mask1 = (float*)alloc(2097152);
  float* scaleB = (float*)alloc(2097152);
  float* mnextB = (float*)alloc(2097152);
  float* sums = (float*)alloc(5120);
  float* bnab = (float*)alloc(5120);
  float* feat = (float*)alloc(40960);
  float* z1 = (float*)alloc(16384);

  zero_k<<<40, 256, 0, stream>>>(feat, 10240);

  // split input
  split_k<<<(NB * 256 * 128 + 255) / 256, 256, 0, stream>>>(x, data, mask0);

  // ---------- stage 1 (direct, Ci=1, Co=80, H=256) ----------
  {
    int H = 256;
    int tot = NB * H * WD;
    // fused maskscale (2 rows) + pool -> mask1
    maskscale2_k<<<(tot / 2 + 255) / 256, 256, 0, stream>>>(mask0, scaleB, mnextB,
                                                            mask1, H, 1.0f);
    zero_k<<<1, 256, 0, stream>>>(sums, 160);
    pconv1_k<<<tot / 256, 256, 0, stream>>>(data, mask0, wgt[0], bias[0], scaleB,
                                            mnextB, bufY);
    bnstats_g<<<256, 320, 0, stream>>>(bufY, sums, 10);
    bnfin_k<<<2, 64, 0, stream>>>(sums, gam[0], bet[0], bnab, 80,
                                  1.0f / (NB * (float)H * WD));
    {
      int tz = NB * 2 * 3 * 576 + NB * 128 * 3 * 8;
      zb_k<<<(tz + 255) / 256, 256, 0, stream>>>(xmT0, 128, 3);
    }
    int totp = NB * (H / 2) * WD * (80 / 8);
    bnpool_k<<<(totp + 255) / 256, 256, 0, stream>>>(bufY, bnab, mask1, xmT0, 80, 3, H);
  }

  // ---------- stages 2-4 (MFMA implicit GEMM) ----------
  const int CiS[3] = {80, 160, 320};
  const int NCBS[3] = {3, 5, 10};
  const int CoS[3] = {160, 320, 640};
  const int CopS[3] = {256, 384, 640};
  const int HS[3] = {128, 64, 32};
  bf16_t* xin[3] = {xmT0, xmT1, xmT0};
  bf16_t* xout[3] = {xmT1, xmT0, nullptr};
  float* mIn[3] = {mask1, mask0, mask1};
  float* mOut[3] = {mask0, mask1, mask0 /* scratch for s==2 */};

  for (int s = 0; s < 3; ++s) {
    int H = HS[s], Ci = CiS[s], NCB = NCBS[s], Co = CoS[s], Cop = CopS[s];
    int wtot = 9 * NCB * Cop * 32;
    wtrans_k<<<(wtot + 255) / 256, 256, 0, stream>>>(wgt[s + 1], wt2, Ci, Co, NCB, Cop);
    int tot = NB * H * WD;
    maskscale2_k<<<(tot / 2 + 255) / 256, 256, 0, stream>>>(mIn[s], scaleB, mnextB,
                                                            mOut[s], H, (float)Ci);
    convmfma_k<<<dim3(Cop / 128, NB * (H / 2)), 256, 0, stream>>>(
        xin[s], wt2, bias[s + 1], scaleB, mnextB, bufY, H, NCB, Co, Cop);
    zero_k<<<(2 * Co + 255) / 256, 256, 0, stream>>>(sums, 2 * Co);
    bnstats_g<<<256, 320, 0, stream>>>(bufY, sums, Co / 8);
    bnfin_k<<<(Co + 63) / 64, 64, 0, stream>>>(sums, gam[s + 1], bet[s + 1], bnab, Co,
                                               1.0f / (NB * (float)H * WD));
    if (s < 2) {
      int Hpn = H / 2, NCBn = NCBS[s + 1];
      int tz = NB * 2 * NCBn * 576 + NB * Hpn * NCBn * 8;
      zb_k<<<(tz + 255) / 256, 256, 0, stream>>>(xout[s], Hpn, NCBn);
      int totp = NB * (H / 2) * WD * (Co / 8);
      bnpool_k<<<(totp + 255) / 256, 256, 0, stream>>>(bufY, bnab, mOut[s], xout[s], Co,
                                                       NCBn, H);
    } else {
      bnfeat_k<<<dim3(16, 5, 16), 128, 0, stream>>>(bufY, bnab, feat);
    }
  }

  fc1_k<<<16, 256, 0, stream>>>(feat, fw1, fb1, z1);
  fc2h_k<<<16, 128, 0, stream>>>(z1, fw2, fb2, hw, hb, (float*)d_out);
}